// Round 5
// baseline (293.957 us; speedup 1.0000x reference)
//
#include <hip/hip_runtime.h>
#include <hip/hip_bf16.h>
#include <math.h>

#define NV 64
#define ND 64
#define NTOK 8192
#define LN_EPS 1e-5f
#define SROW 4096
#define WROW 4096
#define MT 32                   // fused stage2 token tile -> grid 256
#define PF 8                    // register prefetch depth (chunks of K=32)

typedef __attribute__((ext_vector_type(8))) short s8v;    // 8 bf16 = 4 VGPR
typedef __attribute__((ext_vector_type(4))) float f4v;    // MFMA C/D
typedef __attribute__((ext_vector_type(4))) int   i4v;

__device__ __forceinline__ float sigm_f(float x) {
    return __builtin_amdgcn_rcpf(1.f + __expf(-x));
}
__device__ __forceinline__ float elu_f(float x)  { return x > 0.f ? x : (__expf(x) - 1.f); }

__device__ __forceinline__ float bf16_to_f(unsigned short s) {
    union { unsigned int u; float f; } c; c.u = ((unsigned int)s) << 16;
    return c.f;
}
__device__ __forceinline__ unsigned short bf16_rn(float f) {
    union { float f; unsigned int u; } c; c.f = f;
    return (unsigned short)((c.u + 0x8000u) >> 16);
}

// ---------------- Prepack: weight transposes via LDS tiles (coalesced R+W)
// b<64: W2/Wg per-v transposes -> bf16 w2b/wgb
// 64<=b<192: wct[n][k] = [Wn1|Wns]^T bf16
// b>=192: Wn2T/WngT f32 transposes (for fused tail float4 dots)
__global__ __launch_bounds__(256) void vsn_prepack(
    const float* __restrict__ W2, const float* __restrict__ Wg,
    const float* __restrict__ Wn1, const float* __restrict__ Wns,
    const float* __restrict__ Wn2, const float* __restrict__ Wng,
    short* __restrict__ w2b, short* __restrict__ wgb,
    short* __restrict__ wct,
    float* __restrict__ Wn2T, float* __restrict__ WngT)
{
    __shared__ float T[64][65];
    const int b = blockIdx.x, t = threadIdx.x;

    if (b < 64) {
        const float* src = W2 + (size_t)b * 4096;
        short* dst = w2b + (size_t)b * 4096;
        #pragma unroll
        for (int pass = 0; pass < 2; ++pass) {
            #pragma unroll
            for (int i = 0; i < 16; ++i) {
                int id = i * 256 + t;
                T[id & 63][id >> 6] = src[id];
            }
            __syncthreads();
            #pragma unroll
            for (int i = 0; i < 16; ++i) {
                int id = i * 256 + t;
                dst[id] = (short)bf16_rn(T[id >> 6][id & 63]);
            }
            __syncthreads();
            src = Wg + (size_t)b * 4096;
            dst = wgb + (size_t)b * 4096;
        }
    } else if (b < 192) {
        int tb = b - 64;
        int half = tb >> 6, kt = tb & 63;
        const float* src = (half == 0 ? Wn1 : Wns) + (size_t)(kt * 64) * 64;
        #pragma unroll
        for (int i = 0; i < 16; ++i) {
            int id = i * 256 + t;
            T[id & 63][id >> 6] = src[id];
        }
        __syncthreads();
        #pragma unroll
        for (int i = 0; i < 16; ++i) {
            int id = i * 256 + t;
            int n = id >> 6, r = id & 63;
            wct[(size_t)(half * 64 + n) * WROW + kt * 64 + r] = (short)bf16_rn(T[n][r]);
        }
    } else {
        const float* src = (b == 192 ? Wn2 : Wng);
        float* dst = (b == 192 ? Wn2T : WngT);
        #pragma unroll
        for (int i = 0; i < 16; ++i) {
            int id = i * 256 + t;
            T[id & 63][id >> 6] = src[id];      // T[j][k] = src[k*64+j]
        }
        __syncthreads();
        #pragma unroll
        for (int i = 0; i < 16; ++i) {
            int id = i * 256 + t;
            dst[id] = T[id >> 6][id & 63];      // dst[j][k] = src[k][j]
        }
    }
}

// ---------------- Stage 1: verified round-0 version (~50us). UNCHANGED.
__global__ __launch_bounds__(256) void vsn_stage1(
    const float* __restrict__ x,
    const float* __restrict__ W1, const float* __restrict__ b1,
    const short* __restrict__ w2b, const short* __restrict__ wgb,
    const float* __restrict__ b2, const float* __restrict__ bg,
    const float* __restrict__ Wsk, const float* __restrict__ bsk,
    const float* __restrict__ gamma, const float* __restrict__ beta,
    unsigned short* __restrict__ stb)
{
    const int t = threadIdx.x;
    const int wave = t >> 6, lane = t & 63;
    const int m16 = lane & 15, quad = lane >> 4;
    const int v = blockIdx.y * 4 + wave;

    __shared__ float xs[4][32];
    __shared__ __align__(16) unsigned short h2s[4][32][72];

    float w1k[2][8], b1k[2][8];
    #pragma unroll
    for (int kt = 0; kt < 2; ++kt) {
        *(float4*)&w1k[kt][0] = *(const float4*)(W1 + v * 64 + kt * 32 + quad * 8);
        *(float4*)&w1k[kt][4] = *(const float4*)(W1 + v * 64 + kt * 32 + quad * 8 + 4);
        *(float4*)&b1k[kt][0] = *(const float4*)(b1 + v * 64 + kt * 32 + quad * 8);
        *(float4*)&b1k[kt][4] = *(const float4*)(b1 + v * 64 + kt * 32 + quad * 8 + 4);
    }
    float b2d[4], bgd[4], wskd[4], bskd[4], gamd[4], betd[4];
    #pragma unroll
    for (int ni = 0; ni < 4; ++ni) {
        int d = v * 64 + ni * 16 + m16;
        b2d[ni] = b2[d]; bgd[ni] = bg[d]; wskd[ni] = Wsk[d]; bskd[ni] = bsk[d];
        gamd[ni] = gamma[d]; betd[ni] = beta[d];
    }
    const size_t wb = (size_t)v * 4096;

    for (int tt4 = 0; tt4 < 4; ++tt4) {
        const int tile0 = blockIdx.x * 128 + tt4 * 32;

        if (lane < 32) xs[wave][lane] = x[(size_t)(tile0 + lane) * NV + v];

        s8v a[2][2];
        #pragma unroll
        for (int kt = 0; kt < 2; ++kt)
            #pragma unroll
            for (int mi = 0; mi < 2; ++mi) {
                float xv = xs[wave][mi * 16 + m16];
                float h[8];
                #pragma unroll
                for (int j = 0; j < 8; ++j) h[j] = elu_f(fmaf(xv, w1k[kt][j], b1k[kt][j]));
                i4v av;
                #pragma unroll
                for (int p = 0; p < 4; ++p) {
                    unsigned int u0 = __float_as_uint(h[2 * p]);
                    unsigned int u1 = __float_as_uint(h[2 * p + 1]);
                    av[p] = (int)((u1 & 0xffff0000u) | (u0 >> 16));
                }
                a[mi][kt] = *(s8v*)&av;
            }

        f4v hacc[2][4];
        #pragma unroll
        for (int mi = 0; mi < 2; ++mi)
            #pragma unroll
            for (int ni = 0; ni < 4; ++ni) hacc[mi][ni] = (f4v){0.f, 0.f, 0.f, 0.f};
        #pragma unroll
        for (int ni = 0; ni < 4; ++ni)
            #pragma unroll
            for (int kt = 0; kt < 2; ++kt) {
                s8v bh = *(const s8v*)(w2b + wb + (size_t)(ni * 16 + m16) * 64 + kt * 32 + quad * 8);
                #pragma unroll
                for (int mi = 0; mi < 2; ++mi)
                    hacc[mi][ni] = __builtin_amdgcn_mfma_f32_16x16x32_bf16(a[mi][kt], bh, hacc[mi][ni], 0, 0, 0);
            }
        #pragma unroll
        for (int mi = 0; mi < 2; ++mi)
            #pragma unroll
            for (int ni = 0; ni < 4; ++ni)
                #pragma unroll
                for (int r = 0; r < 4; ++r) hacc[mi][ni][r] += b2d[ni];

        #pragma unroll
        for (int mi = 0; mi < 2; ++mi)
            #pragma unroll
            for (int ni = 0; ni < 4; ++ni)
                #pragma unroll
                for (int r = 0; r < 4; ++r)
                    h2s[wave][mi * 16 + quad * 4 + r][ni * 16 + m16] =
                        (unsigned short)(__float_as_uint(hacc[mi][ni][r]) >> 16);

        s8v c[2][2];
        #pragma unroll
        for (int mi = 0; mi < 2; ++mi)
            #pragma unroll
            for (int kt = 0; kt < 2; ++kt)
                c[mi][kt] = *(const s8v*)&h2s[wave][mi * 16 + m16][kt * 32 + quad * 8];

        f4v gacc[2][4];
        #pragma unroll
        for (int mi = 0; mi < 2; ++mi)
            #pragma unroll
            for (int ni = 0; ni < 4; ++ni) gacc[mi][ni] = (f4v){0.f, 0.f, 0.f, 0.f};
        #pragma unroll
        for (int ni = 0; ni < 4; ++ni)
            #pragma unroll
            for (int kt = 0; kt < 2; ++kt) {
                s8v bh = *(const s8v*)(wgb + wb + (size_t)(ni * 16 + m16) * 64 + kt * 32 + quad * 8);
                #pragma unroll
                for (int mi = 0; mi < 2; ++mi)
                    gacc[mi][ni] = __builtin_amdgcn_mfma_f32_16x16x32_bf16(c[mi][kt], bh, gacc[mi][ni], 0, 0, 0);
            }

        {
            float xtok[2][4];
            #pragma unroll
            for (int mi = 0; mi < 2; ++mi)
                #pragma unroll
                for (int r = 0; r < 4; ++r) xtok[mi][r] = xs[wave][mi * 16 + quad * 4 + r];
            #pragma unroll
            for (int mi = 0; mi < 2; ++mi)
                #pragma unroll
                for (int ni = 0; ni < 4; ++ni)
                    #pragma unroll
                    for (int r = 0; r < 4; ++r) {
                        float g = sigm_f(gacc[mi][ni][r] + bgd[ni]);
                        gacc[mi][ni][r] = fmaf(xtok[mi][r], wskd[ni], bskd[ni]) + g * hacc[mi][ni][r];
                    }
        }

        #pragma unroll
        for (int mi = 0; mi < 2; ++mi)
            #pragma unroll
            for (int r = 0; r < 4; ++r) {
                float s0 = gacc[mi][0][r], s1 = gacc[mi][1][r], s2 = gacc[mi][2][r], s3 = gacc[mi][3][r];
                float sum = s0 + s1 + s2 + s3;
                float sq  = s0 * s0 + s1 * s1 + s2 * s2 + s3 * s3;
                #pragma unroll
                for (int m = 1; m < 16; m <<= 1) { sum += __shfl_xor(sum, m); sq += __shfl_xor(sq, m); }
                float mu  = sum * 0.015625f;
                float var = sq * 0.015625f - mu * mu;
                float rs  = __builtin_amdgcn_rsqf(var + LN_EPS);
                size_t base = (size_t)(tile0 + mi * 16 + quad * 4 + r) * SROW + (size_t)v * 64 + m16;
                #pragma unroll
                for (int ni = 0; ni < 4; ++ni)
                    stb[base + ni * 16] =
                        bf16_rn((gacc[mi][ni][r] - mu) * rs * gamd[ni] + betd[ni]);
            }
    }
}

// ---------------- FUSED Stage 2 (barrier-free K-loop): per-wave direct
// global->register fragment loads, PF=8 chunk software pipeline, no LDS and
// no barriers until the tail. Wave w computes tokens[0:32] x cols[w*16:+16]
// over K=4096 (128 chunks of K=32, 2 MFMA each). A-tile (256KB) shared via
// L1 across the 8 waves; B-slice (128KB/wave) L2-resident (shared by all
// 256 blocks). Tail (T0-T4) verified in round 4, unchanged.
__global__ __launch_bounds__(512, 2) void vsn_stage2(
    const unsigned short* __restrict__ stb,   // [8192][SROW]
    const short* __restrict__ wct,            // [128][WROW]
    const float* __restrict__ Wn2T, const float* __restrict__ WngT,
    const float* __restrict__ bn1, const float* __restrict__ bn2,
    const float* __restrict__ bng, const float* __restrict__ bns,
    const float* __restrict__ ngamma, const float* __restrict__ nbeta,
    float* __restrict__ out)
{
    const int t = threadIdx.x;
    const int wave = t >> 6, lane = t & 63;
    const int m16 = lane & 15, quad = lane >> 4;
    const int tok0 = blockIdx.x * MT;

    __shared__ __align__(16) float hw1_s[32 * 68];
    __shared__ __align__(16) float skw_s[32 * 68];
    __shared__ __align__(16) float hw2_s[32 * 68];
    __shared__ __align__(16) float s2_s[32 * 68];
    __shared__ __align__(16) float w_s[32 * 68];

    // per-lane fragment base pointers (16B loads at chunk*64B stride)
    const unsigned short* pa0 = stb + (size_t)(tok0 + m16) * SROW + quad * 8;
    const unsigned short* pa1 = pa0 + 16 * SROW;
    const short*          pb  = wct + (size_t)(wave * 16 + m16) * WROW + quad * 8;

    f4v acc0 = (f4v){0.f, 0.f, 0.f, 0.f};
    f4v acc1 = (f4v){0.f, 0.f, 0.f, 0.f};

    s8v ra0[PF], ra1[PF], rb[PF];
    #pragma unroll
    for (int p = 0; p < PF; ++p) {
        ra0[p] = *(const s8v*)(pa0 + p * 32);
        ra1[p] = *(const s8v*)(pa1 + p * 32);
        rb[p]  = *(const s8v*)(pb  + p * 32);
    }

    // main loop: compute chunk kc+p, refill slot p with chunk kc+PF+p
    for (int kc = 0; kc < 128 - PF; kc += PF) {
        #pragma unroll
        for (int p = 0; p < PF; ++p) {
            acc0 = __builtin_amdgcn_mfma_f32_16x16x32_bf16(ra0[p], rb[p], acc0, 0, 0, 0);
            acc1 = __builtin_amdgcn_mfma_f32_16x16x32_bf16(ra1[p], rb[p], acc1, 0, 0, 0);
            const int nc = kc + PF + p;
            ra0[p] = *(const s8v*)(pa0 + (size_t)nc * 32);
            ra1[p] = *(const s8v*)(pa1 + (size_t)nc * 32);
            rb[p]  = *(const s8v*)(pb  + (size_t)nc * 32);
        }
    }
    #pragma unroll
    for (int p = 0; p < PF; ++p) {
        acc0 = __builtin_amdgcn_mfma_f32_16x16x32_bf16(ra0[p], rb[p], acc0, 0, 0, 0);
        acc1 = __builtin_amdgcn_mfma_f32_16x16x32_bf16(ra1[p], rb[p], acc1, 0, 0, 0);
    }

    // ---- T0: registers -> hw1_s / skw_s
    if (wave < 4) {
        const int col = wave * 16 + m16;
        const float bb = bn1[col];
        #pragma unroll
        for (int r = 0; r < 4; ++r) {
            hw1_s[(quad * 4 + r) * 68 + col]      = elu_f(acc0[r] + bb);
            hw1_s[(16 + quad * 4 + r) * 68 + col] = elu_f(acc1[r] + bb);
        }
    } else {
        const int col = (wave - 4) * 16 + m16;
        const float bb = bns[col];
        #pragma unroll
        for (int r = 0; r < 4; ++r) {
            skw_s[(quad * 4 + r) * 68 + col]      = acc0[r] + bb;
            skw_s[(16 + quad * 4 + r) * 68 + col] = acc1[r] + bb;
        }
    }
    __syncthreads();

    // ---- T1: hw2 = hw1 @ Wn2 + bn2  (32x64, K=64; Wn2T float4 dots)
    #pragma unroll
    for (int i = 0; i < 4; ++i) {
        int oidx = i * 512 + t;
        int tt = oidx >> 6, jj = oidx & 63;
        float a = bn2[jj];
        #pragma unroll
        for (int k4 = 0; k4 < 16; ++k4) {
            float4 h = *(const float4*)&hw1_s[tt * 68 + k4 * 4];
            float4 w4 = *(const float4*)(Wn2T + jj * 64 + k4 * 4);
            a += h.x * w4.x + h.y * w4.y + h.z * w4.z + h.w * w4.w;
        }
        hw2_s[tt * 68 + jj] = a;
    }
    __syncthreads();

    // ---- T2: gw = sigmoid(hw2 @ Wng + bng); s2 = skw + gw*hw2
    #pragma unroll
    for (int i = 0; i < 4; ++i) {
        int oidx = i * 512 + t;
        int tt = oidx >> 6, vv = oidx & 63;
        float a = bng[vv];
        #pragma unroll
        for (int k4 = 0; k4 < 16; ++k4) {
            float4 h = *(const float4*)&hw2_s[tt * 68 + k4 * 4];
            float4 w4 = *(const float4*)(WngT + vv * 64 + k4 * 4);
            a += h.x * w4.x + h.y * w4.y + h.z * w4.z + h.w * w4.w;
        }
        float gw = sigm_f(a);
        s2_s[tt * 68 + vv] = skw_s[tt * 68 + vv] + gw * hw2_s[tt * 68 + vv];
    }
    __syncthreads();

    // ---- T3: LN over v + softmax; 16 lanes per token, 32 tokens
    {
        int tt = t >> 4, l = t & 15;
        float z[4]; float sum = 0.f, sq = 0.f;
        #pragma unroll
        for (int i = 0; i < 4; ++i) { z[i] = s2_s[tt * 68 + l + 16 * i]; sum += z[i]; sq += z[i] * z[i]; }
        #pragma unroll
        for (int m = 1; m < 16; m <<= 1) { sum += __shfl_xor(sum, m); sq += __shfl_xor(sq, m); }
        float mu  = sum * 0.015625f;
        float var = sq * 0.015625f - mu * mu;
        float rs  = __builtin_amdgcn_rsqf(var + LN_EPS);
        float ln[4]; float mx = -1e30f;
        #pragma unroll
        for (int i = 0; i < 4; ++i) {
            ln[i] = (z[i] - mu) * rs * ngamma[l + 16 * i] + nbeta[l + 16 * i];
            mx = fmaxf(mx, ln[i]);
        }
        #pragma unroll
        for (int m = 1; m < 16; m <<= 1) mx = fmaxf(mx, __shfl_xor(mx, m));
        float es = 0.f; float ev[4];
        #pragma unroll
        for (int i = 0; i < 4; ++i) { ev[i] = __expf(ln[i] - mx); es += ev[i]; }
        #pragma unroll
        for (int m = 1; m < 16; m <<= 1) es += __shfl_xor(es, m);
        float inv = __builtin_amdgcn_rcpf(es);
        #pragma unroll
        for (int i = 0; i < 4; ++i) w_s[tt * 68 + l + 16 * i] = ev[i] * inv;
    }
    __syncthreads();

    // ---- T4: weighted sum; wave handles 4 tokens; stb tile is cache-hot
    {
        const int vloc = lane >> 3, d8 = (lane & 7) * 8;
        #pragma unroll
        for (int tk = 0; tk < 4; ++tk) {
            const int tl = wave * 4 + tk;
            const unsigned short* s0 = stb + (size_t)(tok0 + tl) * SROW + d8;
            float a[8];
            #pragma unroll
            for (int j = 0; j < 8; ++j) a[j] = 0.f;
            #pragma unroll
            for (int vc = 0; vc < 8; ++vc) {
                int v = vc * 8 + vloc;
                float w = w_s[tl * 68 + v];
                s8v rr = *(const s8v*)(s0 + v * 64);
                #pragma unroll
                for (int j = 0; j < 8; ++j)
                    a[j] = fmaf(w, bf16_to_f((unsigned short)rr[j]), a[j]);
            }
            #pragma unroll
            for (int m = 8; m <= 32; m <<= 1)
                #pragma unroll
                for (int j = 0; j < 8; ++j) a[j] += __shfl_xor(a[j], m);
            if (lane < 8) {
                float* op = out + (size_t)(tok0 + tl) * 64 + lane * 8;
                *(float4*)op       = make_float4(a[0], a[1], a[2], a[3]);
                *(float4*)(op + 4) = make_float4(a[4], a[5], a[6], a[7]);
            }
        }
    }
}

extern "C" void kernel_launch(void* const* d_in, const int* in_sizes, int n_in,
                              void* d_out, int out_size, void* d_ws, size_t ws_size,
                              hipStream_t stream) {
    const float* x     = (const float*)d_in[0];
    const float* W1    = (const float*)d_in[1];
    const float* b1    = (const float*)d_in[2];
    const float* W2    = (const float*)d_in[3];
    const float* b2    = (const float*)d_in[4];
    const float* Wg    = (const float*)d_in[5];
    const float* bg    = (const float*)d_in[6];
    const float* Wsk   = (const float*)d_in[7];
    const float* bsk   = (const float*)d_in[8];
    const float* gamma = (const float*)d_in[9];
    const float* beta  = (const float*)d_in[10];
    const float* Wn1   = (const float*)d_in[11];
    const float* bn1   = (const float*)d_in[12];
    const float* Wn2   = (const float*)d_in[13];
    const float* bn2   = (const float*)d_in[14];
    const float* Wng   = (const float*)d_in[15];
    const float* bng   = (const float*)d_in[16];
    const float* Wns   = (const float*)d_in[17];
    const float* bns   = (const float*)d_in[18];
    const float* ngam  = (const float*)d_in[19];
    const float* nbet  = (const float*)d_in[20];

    char* ws = (char*)d_ws;
    unsigned short* stb = (unsigned short*)ws;                   // 64 MiB
    short* wct = (short*)(ws + (64u << 20));                     // 1 MiB
    short* w2b = (short*)(ws + (65u << 20));                     // 512 KiB each
    short* wgb = w2b + 262144;
    float* Wn2T = (float*)(ws + (66u << 20));                    // 16 KiB
    float* WngT = Wn2T + 4096;                                   // 16 KiB
    float* outp = (float*)d_out;

    vsn_prepack<<<dim3(194), 256, 0, stream>>>(W2, Wg, Wn1, Wns, Wn2, Wng,
                                               w2b, wgb, wct, Wn2T, WngT);
    vsn_stage1<<<dim3(NTOK / 128, 16), 256, 0, stream>>>(
        x, W1, b1, w2b, wgb, b2, bg, Wsk, bsk, gamma, beta, stb);
    vsn_stage2<<<dim3(NTOK / MT), 512, 0, stream>>>(
        stb, wct, Wn2T, WngT, bn1, bn2, bng, bns, ngam, nbet, outp);
}

// Round 6
// 270.743 us; speedup vs baseline: 1.0857x; 1.0857x over previous
//
#include <hip/hip_runtime.h>
#include <hip/hip_bf16.h>
#include <math.h>

#define NV 64
#define ND 64
#define NTOK 8192
#define LN_EPS 1e-5f
#define SROW 4128               // 4096 + 32: breaks 8KB power-of-2 row stride
#define WROW 4128
#define KSPLIT 8
#define KR2 (4096 / KSPLIT)     // 512
#define BK 64
#define NKC (KR2 / BK)          // 8
#define PROW2 1040              // 1024 + 16

typedef __attribute__((ext_vector_type(8))) short s8v;    // 8 bf16 = 4 VGPR
typedef __attribute__((ext_vector_type(4))) float f4v;    // MFMA C/D
typedef __attribute__((ext_vector_type(4))) int   i4v;

__device__ __forceinline__ float sigm_f(float x) {
    return __builtin_amdgcn_rcpf(1.f + __expf(-x));
}
__device__ __forceinline__ float elu_f(float x)  { return x > 0.f ? x : (__expf(x) - 1.f); }

__device__ __forceinline__ float bf16_to_f(unsigned short s) {
    union { unsigned int u; float f; } c; c.u = ((unsigned int)s) << 16;
    return c.f;
}
__device__ __forceinline__ unsigned short bf16_rn(float f) {
    union { float f; unsigned int u; } c; c.f = f;
    return (unsigned short)((c.u + 0x8000u) >> 16);
}
// async global->LDS 16B (lds base wave-uniform; lane l writes base + l*16B)
__device__ __forceinline__ void async16(const void* g, void* l) {
    __builtin_amdgcn_global_load_lds(
        (const __attribute__((address_space(1))) unsigned int*)g,
        (__attribute__((address_space(3))) unsigned int*)l,
        16, 0, 0);
}

// ---------------- Prepack: weight transposes via LDS tiles (coalesced R+W)
__global__ __launch_bounds__(256) void vsn_prepack(
    const float* __restrict__ W2, const float* __restrict__ Wg,
    const float* __restrict__ Wn1, const float* __restrict__ Wns,
    short* __restrict__ w2b, short* __restrict__ wgb,
    short* __restrict__ wct)
{
    __shared__ float T[64][65];
    const int b = blockIdx.x, t = threadIdx.x;

    if (b < 64) {
        const float* src = W2 + (size_t)b * 4096;
        short* dst = w2b + (size_t)b * 4096;
        #pragma unroll
        for (int pass = 0; pass < 2; ++pass) {
            #pragma unroll
            for (int i = 0; i < 16; ++i) {
                int id = i * 256 + t;
                T[id & 63][id >> 6] = src[id];
            }
            __syncthreads();
            #pragma unroll
            for (int i = 0; i < 16; ++i) {
                int id = i * 256 + t;
                dst[id] = (short)bf16_rn(T[id >> 6][id & 63]);
            }
            __syncthreads();
            src = Wg + (size_t)b * 4096;
            dst = wgb + (size_t)b * 4096;
        }
    } else {
        int tb = b - 64;
        int half = tb >> 6, kt = tb & 63;
        const float* src = (half == 0 ? Wn1 : Wns) + (size_t)(kt * 64) * 64;
        #pragma unroll
        for (int i = 0; i < 16; ++i) {
            int id = i * 256 + t;
            T[id & 63][id >> 6] = src[id];
        }
        __syncthreads();
        #pragma unroll
        for (int i = 0; i < 16; ++i) {
            int id = i * 256 + t;
            int n = id >> 6, r = id & 63;
            wct[(size_t)(half * 64 + n) * WROW + kt * 64 + r] = (short)bf16_rn(T[n][r]);
        }
    }
}

// ---------------- Stage 1: round-0 verified core + LDS-staged vectorized
// epilogue stores (32x global_store_short -> 4x ds_read_b128 + 4x dwordx4).
__global__ __launch_bounds__(256, 4) void vsn_stage1(
    const float* __restrict__ x,
    const float* __restrict__ W1, const float* __restrict__ b1,
    const short* __restrict__ w2b, const short* __restrict__ wgb,
    const float* __restrict__ b2, const float* __restrict__ bg,
    const float* __restrict__ Wsk, const float* __restrict__ bsk,
    const float* __restrict__ gamma, const float* __restrict__ beta,
    unsigned short* __restrict__ stb)
{
    const int t = threadIdx.x;
    const int wave = t >> 6, lane = t & 63;
    const int m16 = lane & 15, quad = lane >> 4;
    const int v = blockIdx.y * 4 + wave;

    __shared__ float xs[4][32];
    __shared__ __align__(16) unsigned short h2s[4][32][72];

    float w1k[2][8], b1k[2][8];
    #pragma unroll
    for (int kt = 0; kt < 2; ++kt) {
        *(float4*)&w1k[kt][0] = *(const float4*)(W1 + v * 64 + kt * 32 + quad * 8);
        *(float4*)&w1k[kt][4] = *(const float4*)(W1 + v * 64 + kt * 32 + quad * 8 + 4);
        *(float4*)&b1k[kt][0] = *(const float4*)(b1 + v * 64 + kt * 32 + quad * 8);
        *(float4*)&b1k[kt][4] = *(const float4*)(b1 + v * 64 + kt * 32 + quad * 8 + 4);
    }
    float b2d[4], bgd[4], wskd[4], bskd[4], gamd[4], betd[4];
    #pragma unroll
    for (int ni = 0; ni < 4; ++ni) {
        int d = v * 64 + ni * 16 + m16;
        b2d[ni] = b2[d]; bgd[ni] = bg[d]; wskd[ni] = Wsk[d]; bskd[ni] = bsk[d];
        gamd[ni] = gamma[d]; betd[ni] = beta[d];
    }
    const size_t wb = (size_t)v * 4096;

    for (int tt4 = 0; tt4 < 4; ++tt4) {
        const int tile0 = blockIdx.x * 128 + tt4 * 32;

        if (lane < 32) xs[wave][lane] = x[(size_t)(tile0 + lane) * NV + v];

        s8v a[2][2];
        #pragma unroll
        for (int kt = 0; kt < 2; ++kt)
            #pragma unroll
            for (int mi = 0; mi < 2; ++mi) {
                float xv = xs[wave][mi * 16 + m16];
                float h[8];
                #pragma unroll
                for (int j = 0; j < 8; ++j) h[j] = elu_f(fmaf(xv, w1k[kt][j], b1k[kt][j]));
                i4v av;
                #pragma unroll
                for (int p = 0; p < 4; ++p) {
                    unsigned int u0 = __float_as_uint(h[2 * p]);
                    unsigned int u1 = __float_as_uint(h[2 * p + 1]);
                    av[p] = (int)((u1 & 0xffff0000u) | (u0 >> 16));
                }
                a[mi][kt] = *(s8v*)&av;
            }

        f4v hacc[2][4];
        #pragma unroll
        for (int mi = 0; mi < 2; ++mi)
            #pragma unroll
            for (int ni = 0; ni < 4; ++ni) hacc[mi][ni] = (f4v){0.f, 0.f, 0.f, 0.f};
        #pragma unroll
        for (int ni = 0; ni < 4; ++ni)
            #pragma unroll
            for (int kt = 0; kt < 2; ++kt) {
                s8v bh = *(const s8v*)(w2b + wb + (size_t)(ni * 16 + m16) * 64 + kt * 32 + quad * 8);
                #pragma unroll
                for (int mi = 0; mi < 2; ++mi)
                    hacc[mi][ni] = __builtin_amdgcn_mfma_f32_16x16x32_bf16(a[mi][kt], bh, hacc[mi][ni], 0, 0, 0);
            }
        #pragma unroll
        for (int mi = 0; mi < 2; ++mi)
            #pragma unroll
            for (int ni = 0; ni < 4; ++ni)
                #pragma unroll
                for (int r = 0; r < 4; ++r) hacc[mi][ni][r] += b2d[ni];

        #pragma unroll
        for (int mi = 0; mi < 2; ++mi)
            #pragma unroll
            for (int ni = 0; ni < 4; ++ni)
                #pragma unroll
                for (int r = 0; r < 4; ++r)
                    h2s[wave][mi * 16 + quad * 4 + r][ni * 16 + m16] =
                        (unsigned short)(__float_as_uint(hacc[mi][ni][r]) >> 16);

        s8v c[2][2];
        #pragma unroll
        for (int mi = 0; mi < 2; ++mi)
            #pragma unroll
            for (int kt = 0; kt < 2; ++kt)
                c[mi][kt] = *(const s8v*)&h2s[wave][mi * 16 + m16][kt * 32 + quad * 8];

        f4v gacc[2][4];
        #pragma unroll
        for (int mi = 0; mi < 2; ++mi)
            #pragma unroll
            for (int ni = 0; ni < 4; ++ni) gacc[mi][ni] = (f4v){0.f, 0.f, 0.f, 0.f};
        #pragma unroll
        for (int ni = 0; ni < 4; ++ni)
            #pragma unroll
            for (int kt = 0; kt < 2; ++kt) {
                s8v bh = *(const s8v*)(wgb + wb + (size_t)(ni * 16 + m16) * 64 + kt * 32 + quad * 8);
                #pragma unroll
                for (int mi = 0; mi < 2; ++mi)
                    gacc[mi][ni] = __builtin_amdgcn_mfma_f32_16x16x32_bf16(c[mi][kt], bh, gacc[mi][ni], 0, 0, 0);
            }

        {
            float xtok[2][4];
            #pragma unroll
            for (int mi = 0; mi < 2; ++mi)
                #pragma unroll
                for (int r = 0; r < 4; ++r) xtok[mi][r] = xs[wave][mi * 16 + quad * 4 + r];
            #pragma unroll
            for (int mi = 0; mi < 2; ++mi)
                #pragma unroll
                for (int ni = 0; ni < 4; ++ni)
                    #pragma unroll
                    for (int r = 0; r < 4; ++r) {
                        float g = sigm_f(gacc[mi][ni][r] + bgd[ni]);
                        gacc[mi][ni][r] = fmaf(xtok[mi][r], wskd[ni], bskd[ni]) + g * hacc[mi][ni][r];
                    }
        }

        // LN: compute + stage normalized bf16 into h2s[wave] (h2 data is dead;
        // wave-local RW, no barrier needed)
        #pragma unroll
        for (int mi = 0; mi < 2; ++mi)
            #pragma unroll
            for (int r = 0; r < 4; ++r) {
                float s0 = gacc[mi][0][r], s1 = gacc[mi][1][r], s2 = gacc[mi][2][r], s3 = gacc[mi][3][r];
                float sum = s0 + s1 + s2 + s3;
                float sq  = s0 * s0 + s1 * s1 + s2 * s2 + s3 * s3;
                #pragma unroll
                for (int m = 1; m < 16; m <<= 1) { sum += __shfl_xor(sum, m); sq += __shfl_xor(sq, m); }
                float mu  = sum * 0.015625f;
                float var = sq * 0.015625f - mu * mu;
                float rs  = __builtin_amdgcn_rsqf(var + LN_EPS);
                #pragma unroll
                for (int ni = 0; ni < 4; ++ni)
                    h2s[wave][mi * 16 + quad * 4 + r][ni * 16 + m16] =
                        bf16_rn((gacc[mi][ni][r] - mu) * rs * gamd[ni] + betd[ni]);
            }

        // vectorized writeout: per i, 8 full token rows x 128B contiguous
        {
            const int tr = lane >> 3, c8 = (lane & 7) * 8;
            #pragma unroll
            for (int i = 0; i < 4; ++i) {
                const int tok = i * 8 + tr;
                s8v vv = *(const s8v*)&h2s[wave][tok][c8];
                *(s8v*)(stb + (size_t)(tile0 + tok) * SROW + v * 64 + c8) = vv;
            }
        }
    }
}

// ---------------- Stage 2a: M=128 x N=128, KSPLIT=8, BK=64, 512 thr / 8 waves.
// Round-3-verified distance-2 prefetch + counted vmcnt. Padded strides.
__global__ __launch_bounds__(512) void vsn_stage2a(
    const unsigned short* __restrict__ stb,   // [8192][SROW]
    const short* __restrict__ wct,            // [128][WROW]
    float* __restrict__ part)                 // [8192][PROW2]
{
    const int t = threadIdx.x;
    const int wave = t >> 6, lane = t & 63;
    const int m16 = lane & 15, quad = lane >> 4;
    const int mw = wave & 3, nw = wave >> 2;
    const int tok0 = blockIdx.x * 128;
    const int s = blockIdx.y;
    const int k0 = s * KR2;

    __shared__ __align__(16) unsigned short Al[2][128 * 64];   // 16KB x2
    __shared__ __align__(16) unsigned short Bl[2][128 * 64];   // 16KB x2

    const int srow = t >> 3;            // 0..63 (+64 for q=1)
    const int schunk = t & 7;           // 16B chunk within the 128B row

    f4v acc[2][4];
    #pragma unroll
    for (int mi = 0; mi < 2; ++mi)
        #pragma unroll
        for (int nj = 0; nj < 4; ++nj) acc[mi][nj] = (f4v){0.f, 0.f, 0.f, 0.f};

    auto STAGE = [&](int buf, int kc) {
        const int kb = k0 + kc * BK;
        #pragma unroll
        for (int q = 0; q < 2; ++q) {
            const int row = srow + q * 64;
            const int sc = (schunk ^ (row & 7)) * 8;   // inverse-swizzled source col
            async16(stb + (size_t)(tok0 + row) * SROW + kb + sc,
                    &Al[buf][q * 4096 + wave * 512]);
            async16(wct + (size_t)row * WROW + kb + sc,
                    &Bl[buf][q * 4096 + wave * 512]);
        }
    };

    STAGE(0, 0);
    STAGE(1, 1);

    for (int kc = 0; kc < NKC; ++kc) {
        const int buf = kc & 1;
        if (kc + 1 < NKC) asm volatile("s_waitcnt vmcnt(4)" ::: "memory");
        else              asm volatile("s_waitcnt vmcnt(0)" ::: "memory");
        __builtin_amdgcn_s_barrier();
        __builtin_amdgcn_sched_barrier(0);

        #pragma unroll
        for (int ks = 0; ks < 2; ++ks) {
            s8v af[2], bfr[4];
            #pragma unroll
            for (int mi = 0; mi < 2; ++mi) {
                int row = mw * 32 + mi * 16 + m16;
                int ch = ((ks * 4 + quad) ^ (row & 7)) * 8;     // swizzled read
                af[mi] = *(const s8v*)&Al[buf][row * 64 + ch];
            }
            #pragma unroll
            for (int nj = 0; nj < 4; ++nj) {
                int row = nw * 64 + nj * 16 + m16;
                int ch = ((ks * 4 + quad) ^ (row & 7)) * 8;
                bfr[nj] = *(const s8v*)&Bl[buf][row * 64 + ch];
            }
            #pragma unroll
            for (int mi = 0; mi < 2; ++mi)
                #pragma unroll
                for (int nj = 0; nj < 4; ++nj)
                    acc[mi][nj] = __builtin_amdgcn_mfma_f32_16x16x32_bf16(af[mi], bfr[nj], acc[mi][nj], 0, 0, 0);
        }

        asm volatile("s_waitcnt lgkmcnt(0)" ::: "memory");
        __builtin_amdgcn_s_barrier();
        __builtin_amdgcn_sched_barrier(0);
        if (kc + 2 < NKC) STAGE(buf, kc + 2);
    }

    #pragma unroll
    for (int mi = 0; mi < 2; ++mi)
        #pragma unroll
        for (int nj = 0; nj < 4; ++nj)
            #pragma unroll
            for (int r = 0; r < 4; ++r)
                part[(size_t)(tok0 + mw * 32 + mi * 16 + quad * 4 + r) * PROW2
                     + s * 128 + nw * 64 + nj * 16 + m16] = acc[mi][nj][r];
}

// ---------------- Stage 2b: reduce 8 contiguous partials, tail GRN, softmax, weighted sum
__global__ __launch_bounds__(256) void vsn_stage2b(
    const unsigned short* __restrict__ stb, const float* __restrict__ part,
    const float* __restrict__ bn1,
    const float* __restrict__ Wn2, const float* __restrict__ bn2,
    const float* __restrict__ Wng, const float* __restrict__ bng,
    const float* __restrict__ bns,
    const float* __restrict__ ngamma, const float* __restrict__ nbeta,
    float* __restrict__ out)
{
    const int t = threadIdx.x;
    const int tok0 = blockIdx.x * 8;
    const int lane = t & 63, wv = t >> 6;

    __shared__ __align__(16) float hw1_s[8][64];
    __shared__ __align__(16) float skw_s[8][64];
    __shared__ __align__(16) float hw2_s[8][64];
    __shared__ float s2_s[8][64];
    __shared__ float w_s[8][64];

    #pragma unroll
    for (int tk = 0; tk < 2; ++tk) {
        int tl = wv * 2 + tk;
        const float* pr = part + (size_t)(tok0 + tl) * PROW2
                        + (lane >> 5) * 128 + (lane & 31) * 4;
        float tv[4] = {0.f, 0.f, 0.f, 0.f};
        #pragma unroll
        for (int i = 0; i < 4; ++i) {
            float4 a = *(const float4*)(pr + i * 256);
            tv[0] += a.x; tv[1] += a.y; tv[2] += a.z; tv[3] += a.w;
        }
        #pragma unroll
        for (int c = 0; c < 4; ++c) tv[c] += __shfl_xor(tv[c], 32);
        if (lane < 16) {
            int j0 = lane * 4;
            float4 bb = *(const float4*)(bn1 + j0);
            hw1_s[tl][j0 + 0] = elu_f(tv[0] + bb.x);
            hw1_s[tl][j0 + 1] = elu_f(tv[1] + bb.y);
            hw1_s[tl][j0 + 2] = elu_f(tv[2] + bb.z);
            hw1_s[tl][j0 + 3] = elu_f(tv[3] + bb.w);
        } else if (lane < 32) {
            int j0 = (lane - 16) * 4;
            float4 bb = *(const float4*)(bns + j0);
            skw_s[tl][j0 + 0] = tv[0] + bb.x;
            skw_s[tl][j0 + 1] = tv[1] + bb.y;
            skw_s[tl][j0 + 2] = tv[2] + bb.z;
            skw_s[tl][j0 + 3] = tv[3] + bb.w;
        }
    }
    __syncthreads();

    #pragma unroll
    for (int i = 0; i < 2; ++i) {
        int oidx = i * 256 + t;
        int tt = oidx >> 6, jj = oidx & 63;
        float acc = bn2[jj];
        #pragma unroll
        for (int k4 = 0; k4 < 16; ++k4) {
            float4 h = *(const float4*)&hw1_s[tt][k4 * 4];
            acc += h.x * Wn2[(k4*4+0)*64+jj] + h.y * Wn2[(k4*4+1)*64+jj]
                 + h.z * Wn2[(k4*4+2)*64+jj] + h.w * Wn2[(k4*4+3)*64+jj];
        }
        hw2_s[tt][jj] = acc;
    }
    __syncthreads();

    #pragma unroll
    for (int i = 0; i < 2; ++i) {
        int oidx = i * 256 + t;
        int tt = oidx >> 6, vv = oidx & 63;
        float acc = bng[vv];
        #pragma unroll
        for (int k4 = 0; k4 < 16; ++k4) {
            float4 h = *(const float4*)&hw2_s[tt][k4 * 4];
            acc += h.x * Wng[(k4*4+0)*64+vv] + h.y * Wng[(k4*4+1)*64+vv]
                 + h.z * Wng[(k4*4+2)*64+vv] + h.w * Wng[(k4*4+3)*64+vv];
        }
        float gw = sigm_f(acc);
        s2_s[tt][vv] = skw_s[tt][vv] + gw * hw2_s[tt][vv];
    }
    __syncthreads();

    const int vloc = lane >> 3, d8 = (lane & 7) * 8;
    s8v r0[8], r1[8];
    {
        const short* s0 = (const short*)stb + (size_t)(tok0 + wv * 2) * SROW + d8;
        const short* s1 = s0 + SROW;
        #pragma unroll
        for (int vc = 0; vc < 8; ++vc) {
            r0[vc] = *(const s8v*)(s0 + (vc * 8 + vloc) * 64);
            r1[vc] = *(const s8v*)(s1 + (vc * 8 + vloc) * 64);
        }
    }

    if (t < 128) {
        int tt = t >> 4, l = t & 15;
        float z[4]; float sum = 0.f, sq = 0.f;
        #pragma unroll
        for (int i = 0; i < 4; ++i) { z[i] = s2_s[tt][l + 16 * i]; sum += z[i]; sq += z[i] * z[i]; }
        #pragma unroll
        for (int m = 1; m < 16; m <<= 1) { sum += __shfl_xor(sum, m); sq += __shfl_xor(sq, m); }
        float mu  = sum * 0.015625f;
        float var = sq * 0.015625f - mu * mu;
        float rs  = __builtin_amdgcn_rsqf(var + LN_EPS);
        float ln[4]; float mx = -1e30f;
        #pragma unroll
        for (int i = 0; i < 4; ++i) {
            ln[i] = (z[i] - mu) * rs * ngamma[l + 16 * i] + nbeta[l + 16 * i];
            mx = fmaxf(mx, ln[i]);
        }
        #pragma unroll
        for (int m = 1; m < 16; m <<= 1) mx = fmaxf(mx, __shfl_xor(mx, m));
        float es = 0.f; float ev[4];
        #pragma unroll
        for (int i = 0; i < 4; ++i) { ev[i] = __expf(ln[i] - mx); es += ev[i]; }
        #pragma unroll
        for (int m = 1; m < 16; m <<= 1) es += __shfl_xor(es, m);
        float inv = __builtin_amdgcn_rcpf(es);
        #pragma unroll
        for (int i = 0; i < 4; ++i) w_s[tt][l + 16 * i] = ev[i] * inv;
    }
    __syncthreads();

    {
        float acc0[8], acc1[8];
        #pragma unroll
        for (int j = 0; j < 8; ++j) { acc0[j] = 0.f; acc1[j] = 0.f; }
        #pragma unroll
        for (int vc = 0; vc < 8; ++vc) {
            int v = vc * 8 + vloc;
            float w0 = w_s[wv * 2][v], w1 = w_s[wv * 2 + 1][v];
            #pragma unroll
            for (int j = 0; j < 8; ++j) {
                acc0[j] = fmaf(w0, bf16_to_f((unsigned short)r0[vc][j]), acc0[j]);
                acc1[j] = fmaf(w1, bf16_to_f((unsigned short)r1[vc][j]), acc1[j]);
            }
        }
        #pragma unroll
        for (int m = 8; m <= 32; m <<= 1)
            #pragma unroll
            for (int j = 0; j < 8; ++j) {
                acc0[j] += __shfl_xor(acc0[j], m);
                acc1[j] += __shfl_xor(acc1[j], m);
            }
        if (lane < 8) {
            float* op = out + (size_t)(tok0 + wv * 2) * 64 + lane * 8;
            *(float4*)op       = make_float4(acc0[0], acc0[1], acc0[2], acc0[3]);
            *(float4*)(op + 4) = make_float4(acc0[4], acc0[5], acc0[6], acc0[7]);
            op += 64;
            *(float4*)op       = make_float4(acc1[0], acc1[1], acc1[2], acc1[3]);
            *(float4*)(op + 4) = make_float4(acc1[4], acc1[5], acc1[6], acc1[7]);
        }
    }
}

extern "C" void kernel_launch(void* const* d_in, const int* in_sizes, int n_in,
                              void* d_out, int out_size, void* d_ws, size_t ws_size,
                              hipStream_t stream) {
    const float* x     = (const float*)d_in[0];
    const float* W1    = (const float*)d_in[1];
    const float* b1    = (const float*)d_in[2];
    const float* W2    = (const float*)d_in[3];
    const float* b2    = (const float*)d_in[4];
    const float* Wg    = (const float*)d_in[5];
    const float* bg    = (const float*)d_in[6];
    const float* Wsk   = (const float*)d_in[7];
    const float* bsk   = (const float*)d_in[8];
    const float* gamma = (const float*)d_in[9];
    const float* beta  = (const float*)d_in[10];
    const float* Wn1   = (const float*)d_in[11];
    const float* bn1   = (const float*)d_in[12];
    const float* Wn2   = (const float*)d_in[13];
    const float* bn2   = (const float*)d_in[14];
    const float* Wng   = (const float*)d_in[15];
    const float* bng   = (const float*)d_in[16];
    const float* Wns   = (const float*)d_in[17];
    const float* bns   = (const float*)d_in[18];
    const float* ngam  = (const float*)d_in[19];
    const float* nbet  = (const float*)d_in[20];

    // compact packed layout (16B-aligned offsets), total ~99.0 MB
    char* ws = (char*)d_ws;
    unsigned short* stb = (unsigned short*)ws;                        // 8192*4128*2 = 67,633,152
    short* wct = (short*)(ws + 67633152);                             // 128*4128*2  =  1,056,768
    short* w2b = (short*)(ws + 68689920);                             // 524,288
    short* wgb = (short*)(ws + 69214208);                             // 524,288
    float* part = (float*)(ws + 69738496);                            // 8192*1040*4 = 34,078,720
    float* outp = (float*)d_out;

    vsn_prepack<<<dim3(192), 256, 0, stream>>>(W2, Wg, Wn1, Wns, w2b, wgb, wct);
    vsn_stage1<<<dim3(NTOK / 128, 16), 256, 0, stream>>>(
        x, W1, b1, w2b, wgb, b2, bg, Wsk, bsk, gamma, beta, stb);
    vsn_stage2a<<<dim3(NTOK / 128, KSPLIT), 512, 0, stream>>>(stb, wct, part);
    vsn_stage2b<<<dim3(NTOK / 8), 256, 0, stream>>>(
        stb, part, bn1, Wn2, bn2, Wng, bng, bns, ngam, nbet, outp);
}

// Round 7
// 270.474 us; speedup vs baseline: 1.0868x; 1.0010x over previous
//
#include <hip/hip_runtime.h>
#include <hip/hip_bf16.h>
#include <math.h>

#define NV 64
#define ND 64
#define NTOK 8192
#define LN_EPS 1e-5f
#define SROW 4160               // 4096+64 shorts: stride 8320B = 65*128B (128B-aligned, odd multiple)
#define WROW 4160
#define KSPLIT 8
#define KR2 (4096 / KSPLIT)     // 512
#define BK 64
#define NKC (KR2 / BK)          // 8
#define PROW2 (KSPLIT * 128)    // 1024 (R3-exact)

typedef __attribute__((ext_vector_type(8))) short s8v;    // 8 bf16 = 4 VGPR
typedef __attribute__((ext_vector_type(4))) float f4v;    // MFMA C/D
typedef __attribute__((ext_vector_type(4))) int   i4v;

__device__ __forceinline__ float sigm_f(float x) {
    return __builtin_amdgcn_rcpf(1.f + __expf(-x));
}
__device__ __forceinline__ float elu_f(float x)  { return x > 0.f ? x : (__expf(x) - 1.f); }

__device__ __forceinline__ float bf16_to_f(unsigned short s) {
    union { unsigned int u; float f; } c; c.u = ((unsigned int)s) << 16;
    return c.f;
}
__device__ __forceinline__ unsigned short bf16_rn(float f) {
    union { float f; unsigned int u; } c; c.f = f;
    return (unsigned short)((c.u + 0x8000u) >> 16);
}
// async global->LDS 16B (lds base wave-uniform; lane l writes base + l*16B)
__device__ __forceinline__ void async16(const void* g, void* l) {
    __builtin_amdgcn_global_load_lds(
        (const __attribute__((address_space(1))) unsigned int*)g,
        (__attribute__((address_space(3))) unsigned int*)l,
        16, 0, 0);
}

// ---------------- Prepack: weight transposes via LDS tiles (coalesced R+W)
__global__ __launch_bounds__(256) void vsn_prepack(
    const float* __restrict__ W2, const float* __restrict__ Wg,
    const float* __restrict__ Wn1, const float* __restrict__ Wns,
    short* __restrict__ w2b, short* __restrict__ wgb,
    short* __restrict__ wct)
{
    __shared__ float T[64][65];
    const int b = blockIdx.x, t = threadIdx.x;

    if (b < 64) {
        const float* src = W2 + (size_t)b * 4096;
        short* dst = w2b + (size_t)b * 4096;
        #pragma unroll
        for (int pass = 0; pass < 2; ++pass) {
            #pragma unroll
            for (int i = 0; i < 16; ++i) {
                int id = i * 256 + t;
                T[id & 63][id >> 6] = src[id];
            }
            __syncthreads();
            #pragma unroll
            for (int i = 0; i < 16; ++i) {
                int id = i * 256 + t;
                dst[id] = (short)bf16_rn(T[id >> 6][id & 63]);
            }
            __syncthreads();
            src = Wg + (size_t)b * 4096;
            dst = wgb + (size_t)b * 4096;
        }
    } else {
        int tb = b - 64;
        int half = tb >> 6, kt = tb & 63;
        const float* src = (half == 0 ? Wn1 : Wns) + (size_t)(kt * 64) * 64;
        #pragma unroll
        for (int i = 0; i < 16; ++i) {
            int id = i * 256 + t;
            T[id & 63][id >> 6] = src[id];
        }
        __syncthreads();
        #pragma unroll
        for (int i = 0; i < 16; ++i) {
            int id = i * 256 + t;
            int n = id >> 6, r = id & 63;
            wct[(size_t)(half * 64 + n) * WROW + kt * 64 + r] = (short)bf16_rn(T[n][r]);
        }
    }
}

// ---------------- Stage 1: round-0 verified core + LDS-staged vectorized
// epilogue stores (now 128B-aligned). VGPR 64 / occ ~35% per R6 counters.
__global__ __launch_bounds__(256, 4) void vsn_stage1(
    const float* __restrict__ x,
    const float* __restrict__ W1, const float* __restrict__ b1,
    const short* __restrict__ w2b, const short* __restrict__ wgb,
    const float* __restrict__ b2, const float* __restrict__ bg,
    const float* __restrict__ Wsk, const float* __restrict__ bsk,
    const float* __restrict__ gamma, const float* __restrict__ beta,
    unsigned short* __restrict__ stb)
{
    const int t = threadIdx.x;
    const int wave = t >> 6, lane = t & 63;
    const int m16 = lane & 15, quad = lane >> 4;
    const int v = blockIdx.y * 4 + wave;

    __shared__ float xs[4][32];
    __shared__ __align__(16) unsigned short h2s[4][32][72];

    float w1k[2][8], b1k[2][8];
    #pragma unroll
    for (int kt = 0; kt < 2; ++kt) {
        *(float4*)&w1k[kt][0] = *(const float4*)(W1 + v * 64 + kt * 32 + quad * 8);
        *(float4*)&w1k[kt][4] = *(const float4*)(W1 + v * 64 + kt * 32 + quad * 8 + 4);
        *(float4*)&b1k[kt][0] = *(const float4*)(b1 + v * 64 + kt * 32 + quad * 8);
        *(float4*)&b1k[kt][4] = *(const float4*)(b1 + v * 64 + kt * 32 + quad * 8 + 4);
    }
    float b2d[4], bgd[4], wskd[4], bskd[4], gamd[4], betd[4];
    #pragma unroll
    for (int ni = 0; ni < 4; ++ni) {
        int d = v * 64 + ni * 16 + m16;
        b2d[ni] = b2[d]; bgd[ni] = bg[d]; wskd[ni] = Wsk[d]; bskd[ni] = bsk[d];
        gamd[ni] = gamma[d]; betd[ni] = beta[d];
    }
    const size_t wb = (size_t)v * 4096;

    for (int tt4 = 0; tt4 < 4; ++tt4) {
        const int tile0 = blockIdx.x * 128 + tt4 * 32;

        if (lane < 32) xs[wave][lane] = x[(size_t)(tile0 + lane) * NV + v];

        s8v a[2][2];
        #pragma unroll
        for (int kt = 0; kt < 2; ++kt)
            #pragma unroll
            for (int mi = 0; mi < 2; ++mi) {
                float xv = xs[wave][mi * 16 + m16];
                float h[8];
                #pragma unroll
                for (int j = 0; j < 8; ++j) h[j] = elu_f(fmaf(xv, w1k[kt][j], b1k[kt][j]));
                i4v av;
                #pragma unroll
                for (int p = 0; p < 4; ++p) {
                    unsigned int u0 = __float_as_uint(h[2 * p]);
                    unsigned int u1 = __float_as_uint(h[2 * p + 1]);
                    av[p] = (int)((u1 & 0xffff0000u) | (u0 >> 16));
                }
                a[mi][kt] = *(s8v*)&av;
            }

        f4v hacc[2][4];
        #pragma unroll
        for (int mi = 0; mi < 2; ++mi)
            #pragma unroll
            for (int ni = 0; ni < 4; ++ni) hacc[mi][ni] = (f4v){0.f, 0.f, 0.f, 0.f};
        #pragma unroll
        for (int ni = 0; ni < 4; ++ni)
            #pragma unroll
            for (int kt = 0; kt < 2; ++kt) {
                s8v bh = *(const s8v*)(w2b + wb + (size_t)(ni * 16 + m16) * 64 + kt * 32 + quad * 8);
                #pragma unroll
                for (int mi = 0; mi < 2; ++mi)
                    hacc[mi][ni] = __builtin_amdgcn_mfma_f32_16x16x32_bf16(a[mi][kt], bh, hacc[mi][ni], 0, 0, 0);
            }
        #pragma unroll
        for (int mi = 0; mi < 2; ++mi)
            #pragma unroll
            for (int ni = 0; ni < 4; ++ni)
                #pragma unroll
                for (int r = 0; r < 4; ++r) hacc[mi][ni][r] += b2d[ni];

        #pragma unroll
        for (int mi = 0; mi < 2; ++mi)
            #pragma unroll
            for (int ni = 0; ni < 4; ++ni)
                #pragma unroll
                for (int r = 0; r < 4; ++r)
                    h2s[wave][mi * 16 + quad * 4 + r][ni * 16 + m16] =
                        (unsigned short)(__float_as_uint(hacc[mi][ni][r]) >> 16);

        s8v c[2][2];
        #pragma unroll
        for (int mi = 0; mi < 2; ++mi)
            #pragma unroll
            for (int kt = 0; kt < 2; ++kt)
                c[mi][kt] = *(const s8v*)&h2s[wave][mi * 16 + m16][kt * 32 + quad * 8];

        f4v gacc[2][4];
        #pragma unroll
        for (int mi = 0; mi < 2; ++mi)
            #pragma unroll
            for (int ni = 0; ni < 4; ++ni) gacc[mi][ni] = (f4v){0.f, 0.f, 0.f, 0.f};
        #pragma unroll
        for (int ni = 0; ni < 4; ++ni)
            #pragma unroll
            for (int kt = 0; kt < 2; ++kt) {
                s8v bh = *(const s8v*)(wgb + wb + (size_t)(ni * 16 + m16) * 64 + kt * 32 + quad * 8);
                #pragma unroll
                for (int mi = 0; mi < 2; ++mi)
                    gacc[mi][ni] = __builtin_amdgcn_mfma_f32_16x16x32_bf16(c[mi][kt], bh, gacc[mi][ni], 0, 0, 0);
            }

        {
            float xtok[2][4];
            #pragma unroll
            for (int mi = 0; mi < 2; ++mi)
                #pragma unroll
                for (int r = 0; r < 4; ++r) xtok[mi][r] = xs[wave][mi * 16 + quad * 4 + r];
            #pragma unroll
            for (int mi = 0; mi < 2; ++mi)
                #pragma unroll
                for (int ni = 0; ni < 4; ++ni)
                    #pragma unroll
                    for (int r = 0; r < 4; ++r) {
                        float g = sigm_f(gacc[mi][ni][r] + bgd[ni]);
                        gacc[mi][ni][r] = fmaf(xtok[mi][r], wskd[ni], bskd[ni]) + g * hacc[mi][ni][r];
                    }
        }

        // LN: compute + stage normalized bf16 into h2s[wave] (h2 data dead;
        // wave-local RW, no barrier needed)
        #pragma unroll
        for (int mi = 0; mi < 2; ++mi)
            #pragma unroll
            for (int r = 0; r < 4; ++r) {
                float s0 = gacc[mi][0][r], s1 = gacc[mi][1][r], s2 = gacc[mi][2][r], s3 = gacc[mi][3][r];
                float sum = s0 + s1 + s2 + s3;
                float sq  = s0 * s0 + s1 * s1 + s2 * s2 + s3 * s3;
                #pragma unroll
                for (int m = 1; m < 16; m <<= 1) { sum += __shfl_xor(sum, m); sq += __shfl_xor(sq, m); }
                float mu  = sum * 0.015625f;
                float var = sq * 0.015625f - mu * mu;
                float rs  = __builtin_amdgcn_rsqf(var + LN_EPS);
                #pragma unroll
                for (int ni = 0; ni < 4; ++ni)
                    h2s[wave][mi * 16 + quad * 4 + r][ni * 16 + m16] =
                        bf16_rn((gacc[mi][ni][r] - mu) * rs * gamd[ni] + betd[ni]);
            }

        // vectorized writeout: 8 token rows x 128B contiguous, all 128B-aligned
        {
            const int tr = lane >> 3, c8 = (lane & 7) * 8;
            #pragma unroll
            for (int i = 0; i < 4; ++i) {
                const int tok = i * 8 + tr;
                s8v vv = *(const s8v*)&h2s[wave][tok][c8];
                *(s8v*)(stb + (size_t)(tile0 + tok) * SROW + v * 64 + c8) = vv;
            }
        }
    }
}

// ---------------- Stage 2a: M=128 x N=128, KSPLIT=8, BK=64, 512 thr / 8 waves.
// Round-3-verified distance-2 prefetch + counted vmcnt. Padded (aligned) strides.
__global__ __launch_bounds__(512) void vsn_stage2a(
    const unsigned short* __restrict__ stb,   // [8192][SROW]
    const short* __restrict__ wct,            // [128][WROW]
    float* __restrict__ part)                 // [8192][PROW2]
{
    const int t = threadIdx.x;
    const int wave = t >> 6, lane = t & 63;
    const int m16 = lane & 15, quad = lane >> 4;
    const int mw = wave & 3, nw = wave >> 2;
    const int tok0 = blockIdx.x * 128;
    const int s = blockIdx.y;
    const int k0 = s * KR2;

    __shared__ __align__(16) unsigned short Al[2][128 * 64];   // 16KB x2
    __shared__ __align__(16) unsigned short Bl[2][128 * 64];   // 16KB x2

    const int srow = t >> 3;            // 0..63 (+64 for q=1)
    const int schunk = t & 7;           // 16B chunk within the 128B row

    f4v acc[2][4];
    #pragma unroll
    for (int mi = 0; mi < 2; ++mi)
        #pragma unroll
        for (int nj = 0; nj < 4; ++nj) acc[mi][nj] = (f4v){0.f, 0.f, 0.f, 0.f};

    auto STAGE = [&](int buf, int kc) {
        const int kb = k0 + kc * BK;
        #pragma unroll
        for (int q = 0; q < 2; ++q) {
            const int row = srow + q * 64;
            const int sc = (schunk ^ (row & 7)) * 8;   // inverse-swizzled source col
            async16(stb + (size_t)(tok0 + row) * SROW + kb + sc,
                    &Al[buf][q * 4096 + wave * 512]);
            async16(wct + (size_t)row * WROW + kb + sc,
                    &Bl[buf][q * 4096 + wave * 512]);
        }
    };

    STAGE(0, 0);
    STAGE(1, 1);

    for (int kc = 0; kc < NKC; ++kc) {
        const int buf = kc & 1;
        if (kc + 1 < NKC) asm volatile("s_waitcnt vmcnt(4)" ::: "memory");
        else              asm volatile("s_waitcnt vmcnt(0)" ::: "memory");
        __builtin_amdgcn_s_barrier();
        __builtin_amdgcn_sched_barrier(0);

        #pragma unroll
        for (int ks = 0; ks < 2; ++ks) {
            s8v af[2], bfr[4];
            #pragma unroll
            for (int mi = 0; mi < 2; ++mi) {
                int row = mw * 32 + mi * 16 + m16;
                int ch = ((ks * 4 + quad) ^ (row & 7)) * 8;     // swizzled read
                af[mi] = *(const s8v*)&Al[buf][row * 64 + ch];
            }
            #pragma unroll
            for (int nj = 0; nj < 4; ++nj) {
                int row = nw * 64 + nj * 16 + m16;
                int ch = ((ks * 4 + quad) ^ (row & 7)) * 8;
                bfr[nj] = *(const s8v*)&Bl[buf][row * 64 + ch];
            }
            #pragma unroll
            for (int mi = 0; mi < 2; ++mi)
                #pragma unroll
                for (int nj = 0; nj < 4; ++nj)
                    acc[mi][nj] = __builtin_amdgcn_mfma_f32_16x16x32_bf16(af[mi], bfr[nj], acc[mi][nj], 0, 0, 0);
        }

        asm volatile("s_waitcnt lgkmcnt(0)" ::: "memory");
        __builtin_amdgcn_s_barrier();
        __builtin_amdgcn_sched_barrier(0);
        if (kc + 2 < NKC) STAGE(buf, kc + 2);
    }

    #pragma unroll
    for (int mi = 0; mi < 2; ++mi)
        #pragma unroll
        for (int nj = 0; nj < 4; ++nj)
            #pragma unroll
            for (int r = 0; r < 4; ++r)
                part[(size_t)(tok0 + mw * 32 + mi * 16 + quad * 4 + r) * PROW2
                     + s * 128 + nw * 64 + nj * 16 + m16] = acc[mi][nj][r];
}

// ---------------- Stage 2b: reduce 8 contiguous partials, tail GRN, softmax, weighted sum
__global__ __launch_bounds__(256) void vsn_stage2b(
    const unsigned short* __restrict__ stb, const float* __restrict__ part,
    const float* __restrict__ bn1,
    const float* __restrict__ Wn2, const float* __restrict__ bn2,
    const float* __restrict__ Wng, const float* __restrict__ bng,
    const float* __restrict__ bns,
    const float* __restrict__ ngamma, const float* __restrict__ nbeta,
    float* __restrict__ out)
{
    const int t = threadIdx.x;
    const int tok0 = blockIdx.x * 8;
    const int lane = t & 63, wv = t >> 6;

    __shared__ __align__(16) float hw1_s[8][64];
    __shared__ __align__(16) float skw_s[8][64];
    __shared__ __align__(16) float hw2_s[8][64];
    __shared__ float s2_s[8][64];
    __shared__ float w_s[8][64];

    #pragma unroll
    for (int tk = 0; tk < 2; ++tk) {
        int tl = wv * 2 + tk;
        const float* pr = part + (size_t)(tok0 + tl) * PROW2
                        + (lane >> 5) * 128 + (lane & 31) * 4;
        float tv[4] = {0.f, 0.f, 0.f, 0.f};
        #pragma unroll
        for (int i = 0; i < 4; ++i) {
            float4 a = *(const float4*)(pr + i * 256);
            tv[0] += a.x; tv[1] += a.y; tv[2] += a.z; tv[3] += a.w;
        }
        #pragma unroll
        for (int c = 0; c < 4; ++c) tv[c] += __shfl_xor(tv[c], 32);
        if (lane < 16) {
            int j0 = lane * 4;
            float4 bb = *(const float4*)(bn1 + j0);
            hw1_s[tl][j0 + 0] = elu_f(tv[0] + bb.x);
            hw1_s[tl][j0 + 1] = elu_f(tv[1] + bb.y);
            hw1_s[tl][j0 + 2] = elu_f(tv[2] + bb.z);
            hw1_s[tl][j0 + 3] = elu_f(tv[3] + bb.w);
        } else if (lane < 32) {
            int j0 = (lane - 16) * 4;
            float4 bb = *(const float4*)(bns + j0);
            skw_s[tl][j0 + 0] = tv[0] + bb.x;
            skw_s[tl][j0 + 1] = tv[1] + bb.y;
            skw_s[tl][j0 + 2] = tv[2] + bb.z;
            skw_s[tl][j0 + 3] = tv[3] + bb.w;
        }
    }
    __syncthreads();

    #pragma unroll
    for (int i = 0; i < 2; ++i) {
        int oidx = i * 256 + t;
        int tt = oidx >> 6, jj = oidx & 63;
        float acc = bn2[jj];
        #pragma unroll
        for (int k4 = 0; k4 < 16; ++k4) {
            float4 h = *(const float4*)&hw1_s[tt][k4 * 4];
            acc += h.x * Wn2[(k4*4+0)*64+jj] + h.y * Wn2[(k4*4+1)*64+jj]
                 + h.z * Wn2[(k4*4+2)*64+jj] + h.w * Wn2[(k4*4+3)*64+jj];
        }
        hw2_s[tt][jj] = acc;
    }
    __syncthreads();

    #pragma unroll
    for (int i = 0; i < 2; ++i) {
        int oidx = i * 256 + t;
        int tt = oidx >> 6, vv = oidx & 63;
        float acc = bng[vv];
        #pragma unroll
        for (int k4 = 0; k4 < 16; ++k4) {
            float4 h = *(const float4*)&hw2_s[tt][k4 * 4];
            acc += h.x * Wng[(k4*4+0)*64+vv] + h.y * Wng[(k4*4+1)*64+vv]
                 + h.z * Wng[(k4*4+2)*64+vv] + h.w * Wng[(k4*4+3)*64+vv];
        }
        float gw = sigm_f(acc);
        s2_s[tt][vv] = skw_s[tt][vv] + gw * hw2_s[tt][vv];
    }
    __syncthreads();

    const int vloc = lane >> 3, d8 = (lane & 7) * 8;
    s8v r0[8], r1[8];
    {
        const short* s0 = (const short*)stb + (size_t)(tok0 + wv * 2) * SROW + d8;
        const short* s1 = s0 + SROW;
        #pragma unroll
        for (int vc = 0; vc < 8; ++vc) {
            r0[vc] = *(const s8v*)(s0 + (vc * 8 + vloc) * 64);
            r1[vc] = *(const s8v*)(s1 + (vc * 8 + vloc) * 64);
        }
    }

    if (t < 128) {
        int tt = t >> 4, l = t & 15;
        float z[4]; float sum = 0.f, sq = 0.f;
        #pragma unroll
        for (int i = 0; i < 4; ++i) { z[i] = s2_s[tt][l + 16 * i]; sum += z[i]; sq += z[i] * z[i]; }
        #pragma unroll
        for (int m = 1; m < 16; m <<= 1) { sum += __shfl_xor(sum, m); sq += __shfl_xor(sq, m); }
        float mu  = sum * 0.015625f;
        float var = sq * 0.015625f - mu * mu;
        float rs  = __builtin_amdgcn_rsqf(var + LN_EPS);
        float ln[4]; float mx = -1e30f;
        #pragma unroll
        for (int i = 0; i < 4; ++i) {
            ln[i] = (z[i] - mu) * rs * ngamma[l + 16 * i] + nbeta[l + 16 * i];
            mx = fmaxf(mx, ln[i]);
        }
        #pragma unroll
        for (int m = 1; m < 16; m <<= 1) mx = fmaxf(mx, __shfl_xor(mx, m));
        float es = 0.f; float ev[4];
        #pragma unroll
        for (int i = 0; i < 4; ++i) { ev[i] = __expf(ln[i] - mx); es += ev[i]; }
        #pragma unroll
        for (int m = 1; m < 16; m <<= 1) es += __shfl_xor(es, m);
        float inv = __builtin_amdgcn_rcpf(es);
        #pragma unroll
        for (int i = 0; i < 4; ++i) w_s[tt][l + 16 * i] = ev[i] * inv;
    }
    __syncthreads();

    {
        float acc0[8], acc1[8];
        #pragma unroll
        for (int j = 0; j < 8; ++j) { acc0[j] = 0.f; acc1[j] = 0.f; }
        #pragma unroll
        for (int vc = 0; vc < 8; ++vc) {
            int v = vc * 8 + vloc;
            float w0 = w_s[wv * 2][v], w1 = w_s[wv * 2 + 1][v];
            #pragma unroll
            for (int j = 0; j < 8; ++j) {
                acc0[j] = fmaf(w0, bf16_to_f((unsigned short)r0[vc][j]), acc0[j]);
                acc1[j] = fmaf(w1, bf16_to_f((unsigned short)r1[vc][j]), acc1[j]);
            }
        }
        #pragma unroll
        for (int m = 8; m <= 32; m <<= 1)
            #pragma unroll
            for (int j = 0; j < 8; ++j) {
                acc0[j] += __shfl_xor(acc0[j], m);
                acc1[j] += __shfl_xor(acc1[j], m);
            }
        if (lane < 8) {
            float* op = out + (size_t)(tok0 + wv * 2) * 64 + lane * 8;
            *(float4*)op       = make_float4(acc0[0], acc0[1], acc0[2], acc0[3]);
            *(float4*)(op + 4) = make_float4(acc0[4], acc0[5], acc0[6], acc0[7]);
            op += 64;
            *(float4*)op       = make_float4(acc1[0], acc1[1], acc1[2], acc1[3]);
            *(float4*)(op + 4) = make_float4(acc1[4], acc1[5], acc1[6], acc1[7]);
        }
    }
}

extern "C" void kernel_launch(void* const* d_in, const int* in_sizes, int n_in,
                              void* d_out, int out_size, void* d_ws, size_t ws_size,
                              hipStream_t stream) {
    const float* x     = (const float*)d_in[0];
    const float* W1    = (const float*)d_in[1];
    const float* b1    = (const float*)d_in[2];
    const float* W2    = (const float*)d_in[3];
    const float* b2    = (const float*)d_in[4];
    const float* Wg    = (const float*)d_in[5];
    const float* bg    = (const float*)d_in[6];
    const float* Wsk   = (const float*)d_in[7];
    const float* bsk   = (const float*)d_in[8];
    const float* gamma = (const float*)d_in[9];
    const float* beta  = (const float*)d_in[10];
    const float* Wn1   = (const float*)d_in[11];
    const float* bn1   = (const float*)d_in[12];
    const float* Wn2   = (const float*)d_in[13];
    const float* bn2   = (const float*)d_in[14];
    const float* Wng   = (const float*)d_in[15];
    const float* bng   = (const float*)d_in[16];
    const float* Wns   = (const float*)d_in[17];
    const float* bns   = (const float*)d_in[18];
    const float* ngam  = (const float*)d_in[19];
    const float* nbet  = (const float*)d_in[20];

    // packed layout, all offsets 128B-aligned; total ~99 MiB
    char* ws = (char*)d_ws;
    unsigned short* stb = (unsigned short*)ws;                 // 8192*4160*2 = 68,157,440
    short* wct = (short*)(ws + 68157440);                      // 128*4160*2  =  1,064,960
    short* w2b = (short*)(ws + 69222400);                      // 524,288
    short* wgb = (short*)(ws + 69746688);                      // 524,288
    float* part = (float*)(ws + 70270976);                     // 8192*1024*4 = 33,554,432
    float* outp = (float*)d_out;

    vsn_prepack<<<dim3(192), 256, 0, stream>>>(W2, Wg, Wn1, Wns, w2b, wgb, wct);
    vsn_stage1<<<dim3(NTOK / 128, 16), 256, 0, stream>>>(
        x, W1, b1, w2b, wgb, b2, bg, Wsk, bsk, gamma, beta, stb);
    vsn_stage2a<<<dim3(NTOK / 128, KSPLIT), 512, 0, stream>>>(stb, wct, part);
    vsn_stage2b<<<dim3(NTOK / 8), 256, 0, stream>>>(
        stb, part, bn1, Wn2, bn2, Wng, bng, bns, ngam, nbet, outp);
}

// Round 8
// 187.683 us; speedup vs baseline: 1.5662x; 1.4411x over previous
//
#include <hip/hip_runtime.h>
#include <hip/hip_bf16.h>
#include <math.h>

#define NV 64
#define ND 64
#define NTOK 8192
#define LN_EPS 1e-5f
#define SROW 4096
#define WROW 4096
#define KSPLIT 8
#define KR2 (4096 / KSPLIT)     // 512
#define BK 64
#define NKC (KR2 / BK)          // 8
#define PROW2 (KSPLIT * 128)    // 1024

typedef __attribute__((ext_vector_type(8))) short s8v;    // 8 bf16 = 4 VGPR
typedef __attribute__((ext_vector_type(4))) float f4v;    // MFMA C/D
typedef __attribute__((ext_vector_type(4))) int   i4v;

__device__ __forceinline__ float sigm_f(float x) {
    return __builtin_amdgcn_rcpf(1.f + __expf(-x));
}
__device__ __forceinline__ float elu_f(float x)  { return x > 0.f ? x : (__expf(x) - 1.f); }

__device__ __forceinline__ float bf16_to_f(unsigned short s) {
    union { unsigned int u; float f; } c; c.u = ((unsigned int)s) << 16;
    return c.f;
}
__device__ __forceinline__ unsigned short bf16_rn(float f) {
    union { float f; unsigned int u; } c; c.f = f;
    return (unsigned short)((c.u + 0x8000u) >> 16);
}
// async global->LDS 16B (lds base wave-uniform; lane l writes base + l*16B)
__device__ __forceinline__ void async16(const void* g, void* l) {
    __builtin_amdgcn_global_load_lds(
        (const __attribute__((address_space(1))) unsigned int*)g,
        (__attribute__((address_space(3))) unsigned int*)l,
        16, 0, 0);
}

// ---------------- Prepack: weight transposes via LDS tiles (coalesced R+W)
__global__ __launch_bounds__(256) void vsn_prepack(
    const float* __restrict__ W2, const float* __restrict__ Wg,
    const float* __restrict__ Wn1, const float* __restrict__ Wns,
    short* __restrict__ w2b, short* __restrict__ wgb,
    short* __restrict__ wct)
{
    __shared__ float T[64][65];
    const int b = blockIdx.x, t = threadIdx.x;

    if (b < 64) {
        const float* src = W2 + (size_t)b * 4096;
        short* dst = w2b + (size_t)b * 4096;
        #pragma unroll
        for (int pass = 0; pass < 2; ++pass) {
            #pragma unroll
            for (int i = 0; i < 16; ++i) {
                int id = i * 256 + t;
                T[id & 63][id >> 6] = src[id];
            }
            __syncthreads();
            #pragma unroll
            for (int i = 0; i < 16; ++i) {
                int id = i * 256 + t;
                dst[id] = (short)bf16_rn(T[id >> 6][id & 63]);
            }
            __syncthreads();
            src = Wg + (size_t)b * 4096;
            dst = wgb + (size_t)b * 4096;
        }
    } else {
        int tb = b - 64;
        int half = tb >> 6, kt = tb & 63;
        const float* src = (half == 0 ? Wn1 : Wns) + (size_t)(kt * 64) * 64;
        #pragma unroll
        for (int i = 0; i < 16; ++i) {
            int id = i * 256 + t;
            T[id & 63][id >> 6] = src[id];
        }
        __syncthreads();
        #pragma unroll
        for (int i = 0; i < 16; ++i) {
            int id = i * 256 + t;
            int n = id >> 6, r = id & 63;
            wct[(size_t)(half * 64 + n) * WROW + kt * 64 + r] = (short)bf16_rn(T[n][r]);
        }
    }
}

// ---------------- Stage 1: round-0 verified core; epilogue = LN staged into
// dead h2s buffer + vectorized 128B stores. PLAIN launch_bounds(256) —
// the (256,4) bound in R6/R7 squeezed VGPR 128->64 and caused ~400MB of
// scratch spill traffic (FETCH 291MB / WRITE 210MB). Never bound occupancy
// beyond need.
__global__ __launch_bounds__(256) void vsn_stage1(
    const float* __restrict__ x,
    const float* __restrict__ W1, const float* __restrict__ b1,
    const short* __restrict__ w2b, const short* __restrict__ wgb,
    const float* __restrict__ b2, const float* __restrict__ bg,
    const float* __restrict__ Wsk, const float* __restrict__ bsk,
    const float* __restrict__ gamma, const float* __restrict__ beta,
    unsigned short* __restrict__ stb)
{
    const int t = threadIdx.x;
    const int wave = t >> 6, lane = t & 63;
    const int m16 = lane & 15, quad = lane >> 4;
    const int v = blockIdx.y * 4 + wave;

    __shared__ float xs[4][32];
    __shared__ __align__(16) unsigned short h2s[4][32][72];

    float w1k[2][8], b1k[2][8];
    #pragma unroll
    for (int kt = 0; kt < 2; ++kt) {
        *(float4*)&w1k[kt][0] = *(const float4*)(W1 + v * 64 + kt * 32 + quad * 8);
        *(float4*)&w1k[kt][4] = *(const float4*)(W1 + v * 64 + kt * 32 + quad * 8 + 4);
        *(float4*)&b1k[kt][0] = *(const float4*)(b1 + v * 64 + kt * 32 + quad * 8);
        *(float4*)&b1k[kt][4] = *(const float4*)(b1 + v * 64 + kt * 32 + quad * 8 + 4);
    }
    float b2d[4], bgd[4], wskd[4], bskd[4], gamd[4], betd[4];
    #pragma unroll
    for (int ni = 0; ni < 4; ++ni) {
        int d = v * 64 + ni * 16 + m16;
        b2d[ni] = b2[d]; bgd[ni] = bg[d]; wskd[ni] = Wsk[d]; bskd[ni] = bsk[d];
        gamd[ni] = gamma[d]; betd[ni] = beta[d];
    }
    const size_t wb = (size_t)v * 4096;

    for (int tt4 = 0; tt4 < 4; ++tt4) {
        const int tile0 = blockIdx.x * 128 + tt4 * 32;

        if (lane < 32) xs[wave][lane] = x[(size_t)(tile0 + lane) * NV + v];

        s8v a[2][2];
        #pragma unroll
        for (int kt = 0; kt < 2; ++kt)
            #pragma unroll
            for (int mi = 0; mi < 2; ++mi) {
                float xv = xs[wave][mi * 16 + m16];
                float h[8];
                #pragma unroll
                for (int j = 0; j < 8; ++j) h[j] = elu_f(fmaf(xv, w1k[kt][j], b1k[kt][j]));
                i4v av;
                #pragma unroll
                for (int p = 0; p < 4; ++p) {
                    unsigned int u0 = __float_as_uint(h[2 * p]);
                    unsigned int u1 = __float_as_uint(h[2 * p + 1]);
                    av[p] = (int)((u1 & 0xffff0000u) | (u0 >> 16));
                }
                a[mi][kt] = *(s8v*)&av;
            }

        f4v hacc[2][4];
        #pragma unroll
        for (int mi = 0; mi < 2; ++mi)
            #pragma unroll
            for (int ni = 0; ni < 4; ++ni) hacc[mi][ni] = (f4v){0.f, 0.f, 0.f, 0.f};
        #pragma unroll
        for (int ni = 0; ni < 4; ++ni)
            #pragma unroll
            for (int kt = 0; kt < 2; ++kt) {
                s8v bh = *(const s8v*)(w2b + wb + (size_t)(ni * 16 + m16) * 64 + kt * 32 + quad * 8);
                #pragma unroll
                for (int mi = 0; mi < 2; ++mi)
                    hacc[mi][ni] = __builtin_amdgcn_mfma_f32_16x16x32_bf16(a[mi][kt], bh, hacc[mi][ni], 0, 0, 0);
            }
        #pragma unroll
        for (int mi = 0; mi < 2; ++mi)
            #pragma unroll
            for (int ni = 0; ni < 4; ++ni)
                #pragma unroll
                for (int r = 0; r < 4; ++r) hacc[mi][ni][r] += b2d[ni];

        #pragma unroll
        for (int mi = 0; mi < 2; ++mi)
            #pragma unroll
            for (int ni = 0; ni < 4; ++ni)
                #pragma unroll
                for (int r = 0; r < 4; ++r)
                    h2s[wave][mi * 16 + quad * 4 + r][ni * 16 + m16] =
                        (unsigned short)(__float_as_uint(hacc[mi][ni][r]) >> 16);

        s8v c[2][2];
        #pragma unroll
        for (int mi = 0; mi < 2; ++mi)
            #pragma unroll
            for (int kt = 0; kt < 2; ++kt)
                c[mi][kt] = *(const s8v*)&h2s[wave][mi * 16 + m16][kt * 32 + quad * 8];

        f4v gacc[2][4];
        #pragma unroll
        for (int mi = 0; mi < 2; ++mi)
            #pragma unroll
            for (int ni = 0; ni < 4; ++ni) gacc[mi][ni] = (f4v){0.f, 0.f, 0.f, 0.f};
        #pragma unroll
        for (int ni = 0; ni < 4; ++ni)
            #pragma unroll
            for (int kt = 0; kt < 2; ++kt) {
                s8v bh = *(const s8v*)(wgb + wb + (size_t)(ni * 16 + m16) * 64 + kt * 32 + quad * 8);
                #pragma unroll
                for (int mi = 0; mi < 2; ++mi)
                    gacc[mi][ni] = __builtin_amdgcn_mfma_f32_16x16x32_bf16(c[mi][kt], bh, gacc[mi][ni], 0, 0, 0);
            }

        {
            float xtok[2][4];
            #pragma unroll
            for (int mi = 0; mi < 2; ++mi)
                #pragma unroll
                for (int r = 0; r < 4; ++r) xtok[mi][r] = xs[wave][mi * 16 + quad * 4 + r];
            #pragma unroll
            for (int mi = 0; mi < 2; ++mi)
                #pragma unroll
                for (int ni = 0; ni < 4; ++ni)
                    #pragma unroll
                    for (int r = 0; r < 4; ++r) {
                        float g = sigm_f(gacc[mi][ni][r] + bgd[ni]);
                        gacc[mi][ni][r] = fmaf(xtok[mi][r], wskd[ni], bskd[ni]) + g * hacc[mi][ni][r];
                    }
        }

        // LN: compute + stage normalized bf16 into h2s[wave] (h2 data dead;
        // wave-local RW, no barrier needed)
        #pragma unroll
        for (int mi = 0; mi < 2; ++mi)
            #pragma unroll
            for (int r = 0; r < 4; ++r) {
                float s0 = gacc[mi][0][r], s1 = gacc[mi][1][r], s2 = gacc[mi][2][r], s3 = gacc[mi][3][r];
                float sum = s0 + s1 + s2 + s3;
                float sq  = s0 * s0 + s1 * s1 + s2 * s2 + s3 * s3;
                #pragma unroll
                for (int m = 1; m < 16; m <<= 1) { sum += __shfl_xor(sum, m); sq += __shfl_xor(sq, m); }
                float mu  = sum * 0.015625f;
                float var = sq * 0.015625f - mu * mu;
                float rs  = __builtin_amdgcn_rsqf(var + LN_EPS);
                #pragma unroll
                for (int ni = 0; ni < 4; ++ni)
                    h2s[wave][mi * 16 + quad * 4 + r][ni * 16 + m16] =
                        bf16_rn((gacc[mi][ni][r] - mu) * rs * gamd[ni] + betd[ni]);
            }

        // vectorized writeout: 8 token rows x 128B contiguous per iteration
        {
            const int tr = lane >> 3, c8 = (lane & 7) * 8;
            #pragma unroll
            for (int i = 0; i < 4; ++i) {
                const int tok = i * 8 + tr;
                s8v vv = *(const s8v*)&h2s[wave][tok][c8];
                *(s8v*)(stb + (size_t)(tile0 + tok) * SROW + v * 64 + c8) = vv;
            }
        }
    }
}

// ---------------- Stage 2a: M=128 x N=128, KSPLIT=8, BK=64, 512 thr / 8 waves.
// Round-3-verified distance-2 prefetch + counted vmcnt.
__global__ __launch_bounds__(512) void vsn_stage2a(
    const unsigned short* __restrict__ stb,   // [8192][SROW]
    const short* __restrict__ wct,            // [128][WROW]
    float* __restrict__ part)                 // [8192][PROW2]
{
    const int t = threadIdx.x;
    const int wave = t >> 6, lane = t & 63;
    const int m16 = lane & 15, quad = lane >> 4;
    const int mw = wave & 3, nw = wave >> 2;
    const int tok0 = blockIdx.x * 128;
    const int s = blockIdx.y;
    const int k0 = s * KR2;

    __shared__ __align__(16) unsigned short Al[2][128 * 64];   // 16KB x2
    __shared__ __align__(16) unsigned short Bl[2][128 * 64];   // 16KB x2

    const int srow = t >> 3;            // 0..63 (+64 for q=1)
    const int schunk = t & 7;           // 16B chunk within the 128B row

    f4v acc[2][4];
    #pragma unroll
    for (int mi = 0; mi < 2; ++mi)
        #pragma unroll
        for (int nj = 0; nj < 4; ++nj) acc[mi][nj] = (f4v){0.f, 0.f, 0.f, 0.f};

    auto STAGE = [&](int buf, int kc) {
        const int kb = k0 + kc * BK;
        #pragma unroll
        for (int q = 0; q < 2; ++q) {
            const int row = srow + q * 64;
            const int sc = (schunk ^ (row & 7)) * 8;   // inverse-swizzled source col
            async16(stb + (size_t)(tok0 + row) * SROW + kb + sc,
                    &Al[buf][q * 4096 + wave * 512]);
            async16(wct + (size_t)row * WROW + kb + sc,
                    &Bl[buf][q * 4096 + wave * 512]);
        }
    };

    STAGE(0, 0);
    STAGE(1, 1);

    for (int kc = 0; kc < NKC; ++kc) {
        const int buf = kc & 1;
        if (kc + 1 < NKC) asm volatile("s_waitcnt vmcnt(4)" ::: "memory");
        else              asm volatile("s_waitcnt vmcnt(0)" ::: "memory");
        __builtin_amdgcn_s_barrier();
        __builtin_amdgcn_sched_barrier(0);

        #pragma unroll
        for (int ks = 0; ks < 2; ++ks) {
            s8v af[2], bfr[4];
            #pragma unroll
            for (int mi = 0; mi < 2; ++mi) {
                int row = mw * 32 + mi * 16 + m16;
                int ch = ((ks * 4 + quad) ^ (row & 7)) * 8;     // swizzled read
                af[mi] = *(const s8v*)&Al[buf][row * 64 + ch];
            }
            #pragma unroll
            for (int nj = 0; nj < 4; ++nj) {
                int row = nw * 64 + nj * 16 + m16;
                int ch = ((ks * 4 + quad) ^ (row & 7)) * 8;
                bfr[nj] = *(const s8v*)&Bl[buf][row * 64 + ch];
            }
            #pragma unroll
            for (int mi = 0; mi < 2; ++mi)
                #pragma unroll
                for (int nj = 0; nj < 4; ++nj)
                    acc[mi][nj] = __builtin_amdgcn_mfma_f32_16x16x32_bf16(af[mi], bfr[nj], acc[mi][nj], 0, 0, 0);
        }

        asm volatile("s_waitcnt lgkmcnt(0)" ::: "memory");
        __builtin_amdgcn_s_barrier();
        __builtin_amdgcn_sched_barrier(0);
        if (kc + 2 < NKC) STAGE(buf, kc + 2);
    }

    #pragma unroll
    for (int mi = 0; mi < 2; ++mi)
        #pragma unroll
        for (int nj = 0; nj < 4; ++nj)
            #pragma unroll
            for (int r = 0; r < 4; ++r)
                part[(size_t)(tok0 + mw * 32 + mi * 16 + quad * 4 + r) * PROW2
                     + s * 128 + nw * 64 + nj * 16 + m16] = acc[mi][nj][r];
}

// ---------------- Stage 2b: reduce 8 contiguous partials, tail GRN, softmax, weighted sum
__global__ __launch_bounds__(256) void vsn_stage2b(
    const unsigned short* __restrict__ stb, const float* __restrict__ part,
    const float* __restrict__ bn1,
    const float* __restrict__ Wn2, const float* __restrict__ bn2,
    const float* __restrict__ Wng, const float* __restrict__ bng,
    const float* __restrict__ bns,
    const float* __restrict__ ngamma, const float* __restrict__ nbeta,
    float* __restrict__ out)
{
    const int t = threadIdx.x;
    const int tok0 = blockIdx.x * 8;
    const int lane = t & 63, wv = t >> 6;

    __shared__ __align__(16) float hw1_s[8][64];
    __shared__ __align__(16) float skw_s[8][64];
    __shared__ __align__(16) float hw2_s[8][64];
    __shared__ float s2_s[8][64];
    __shared__ float w_s[8][64];

    #pragma unroll
    for (int tk = 0; tk < 2; ++tk) {
        int tl = wv * 2 + tk;
        const float* pr = part + (size_t)(tok0 + tl) * PROW2
                        + (lane >> 5) * 128 + (lane & 31) * 4;
        float tv[4] = {0.f, 0.f, 0.f, 0.f};
        #pragma unroll
        for (int i = 0; i < 4; ++i) {
            float4 a = *(const float4*)(pr + i * 256);
            tv[0] += a.x; tv[1] += a.y; tv[2] += a.z; tv[3] += a.w;
        }
        #pragma unroll
        for (int c = 0; c < 4; ++c) tv[c] += __shfl_xor(tv[c], 32);
        if (lane < 16) {
            int j0 = lane * 4;
            float4 bb = *(const float4*)(bn1 + j0);
            hw1_s[tl][j0 + 0] = elu_f(tv[0] + bb.x);
            hw1_s[tl][j0 + 1] = elu_f(tv[1] + bb.y);
            hw1_s[tl][j0 + 2] = elu_f(tv[2] + bb.z);
            hw1_s[tl][j0 + 3] = elu_f(tv[3] + bb.w);
        } else if (lane < 32) {
            int j0 = (lane - 16) * 4;
            float4 bb = *(const float4*)(bns + j0);
            skw_s[tl][j0 + 0] = tv[0] + bb.x;
            skw_s[tl][j0 + 1] = tv[1] + bb.y;
            skw_s[tl][j0 + 2] = tv[2] + bb.z;
            skw_s[tl][j0 + 3] = tv[3] + bb.w;
        }
    }
    __syncthreads();

    #pragma unroll
    for (int i = 0; i < 2; ++i) {
        int oidx = i * 256 + t;
        int tt = oidx >> 6, jj = oidx & 63;
        float acc = bn2[jj];
        #pragma unroll
        for (int k4 = 0; k4 < 16; ++k4) {
            float4 h = *(const float4*)&hw1_s[tt][k4 * 4];
            acc += h.x * Wn2[(k4*4+0)*64+jj] + h.y * Wn2[(k4*4+1)*64+jj]
                 + h.z * Wn2[(k4*4+2)*64+jj] + h.w * Wn2[(k4*4+3)*64+jj];
        }
        hw2_s[tt][jj] = acc;
    }
    __syncthreads();

    #pragma unroll
    for (int i = 0; i < 2; ++i) {
        int oidx = i * 256 + t;
        int tt = oidx >> 6, vv = oidx & 63;
        float acc = bng[vv];
        #pragma unroll
        for (int k4 = 0; k4 < 16; ++k4) {
            float4 h = *(const float4*)&hw2_s[tt][k4 * 4];
            acc += h.x * Wng[(k4*4+0)*64+vv] + h.y * Wng[(k4*4+1)*64+vv]
                 + h.z * Wng[(k4*4+2)*64+vv] + h.w * Wng[(k4*4+3)*64+vv];
        }
        float gw = sigm_f(acc);
        s2_s[tt][vv] = skw_s[tt][vv] + gw * hw2_s[tt][vv];
    }
    __syncthreads();

    const int vloc = lane >> 3, d8 = (lane & 7) * 8;
    s8v r0[8], r1[8];
    {
        const short* s0 = (const short*)stb + (size_t)(tok0 + wv * 2) * SROW + d8;
        const short* s1 = s0 + SROW;
        #pragma unroll
        for (int vc = 0; vc < 8; ++vc) {
            r0[vc] = *(const s8v*)(s0 + (vc * 8 + vloc) * 64);
            r1[vc] = *(const s8v*)(s1 + (vc * 8 + vloc) * 64);
        }
    }

    if (t < 128) {
        int tt = t >> 4, l = t & 15;
        float z[4]; float sum = 0.f, sq = 0.f;
        #pragma unroll
        for (int i = 0; i < 4; ++i) { z[i] = s2_s[tt][l + 16 * i]; sum += z[i]; sq += z[i] * z[i]; }
        #pragma unroll
        for (int m = 1; m < 16; m <<= 1) { sum += __shfl_xor(sum, m); sq += __shfl_xor(sq, m); }
        float mu  = sum * 0.015625f;
        float var = sq * 0.015625f - mu * mu;
        float rs  = __builtin_amdgcn_rsqf(var + LN_EPS);
        float ln[4]; float mx = -1e30f;
        #pragma unroll
        for (int i = 0; i < 4; ++i) {
            ln[i] = (z[i] - mu) * rs * ngamma[l + 16 * i] + nbeta[l + 16 * i];
            mx = fmaxf(mx, ln[i]);
        }
        #pragma unroll
        for (int m = 1; m < 16; m <<= 1) mx = fmaxf(mx, __shfl_xor(mx, m));
        float es = 0.f; float ev[4];
        #pragma unroll
        for (int i = 0; i < 4; ++i) { ev[i] = __expf(ln[i] - mx); es += ev[i]; }
        #pragma unroll
        for (int m = 1; m < 16; m <<= 1) es += __shfl_xor(es, m);
        float inv = __builtin_amdgcn_rcpf(es);
        #pragma unroll
        for (int i = 0; i < 4; ++i) w_s[tt][l + 16 * i] = ev[i] * inv;
    }
    __syncthreads();

    {
        float acc0[8], acc1[8];
        #pragma unroll
        for (int j = 0; j < 8; ++j) { acc0[j] = 0.f; acc1[j] = 0.f; }
        #pragma unroll
        for (int vc = 0; vc < 8; ++vc) {
            int v = vc * 8 + vloc;
            float w0 = w_s[wv * 2][v], w1 = w_s[wv * 2 + 1][v];
            #pragma unroll
            for (int j = 0; j < 8; ++j) {
                acc0[j] = fmaf(w0, bf16_to_f((unsigned short)r0[vc][j]), acc0[j]);
                acc1[j] = fmaf(w1, bf16_to_f((unsigned short)r1[vc][j]), acc1[j]);
            }
        }
        #pragma unroll
        for (int m = 8; m <= 32; m <<= 1)
            #pragma unroll
            for (int j = 0; j < 8; ++j) {
                acc0[j] += __shfl_xor(acc0[j], m);
                acc1[j] += __shfl_xor(acc1[j], m);
            }
        if (lane < 8) {
            float* op = out + (size_t)(tok0 + wv * 2) * 64 + lane * 8;
            *(float4*)op       = make_float4(acc0[0], acc0[1], acc0[2], acc0[3]);
            *(float4*)(op + 4) = make_float4(acc0[4], acc0[5], acc0[6], acc0[7]);
            op += 64;
            *(float4*)op       = make_float4(acc1[0], acc1[1], acc1[2], acc1[3]);
            *(float4*)(op + 4) = make_float4(acc1[4], acc1[5], acc1[6], acc1[7]);
        }
    }
}

extern "C" void kernel_launch(void* const* d_in, const int* in_sizes, int n_in,
                              void* d_out, int out_size, void* d_ws, size_t ws_size,
                              hipStream_t stream) {
    const float* x     = (const float*)d_in[0];
    const float* W1    = (const float*)d_in[1];
    const float* b1    = (const float*)d_in[2];
    const float* W2    = (const float*)d_in[3];
    const float* b2    = (const float*)d_in[4];
    const float* Wg    = (const float*)d_in[5];
    const float* bg    = (const float*)d_in[6];
    const float* Wsk   = (const float*)d_in[7];
    const float* bsk   = (const float*)d_in[8];
    const float* gamma = (const float*)d_in[9];
    const float* beta  = (const float*)d_in[10];
    const float* Wn1   = (const float*)d_in[11];
    const float* bn1   = (const float*)d_in[12];
    const float* Wn2   = (const float*)d_in[13];
    const float* bn2   = (const float*)d_in[14];
    const float* Wng   = (const float*)d_in[15];
    const float* bng   = (const float*)d_in[16];
    const float* Wns   = (const float*)d_in[17];
    const float* bns   = (const float*)d_in[18];
    const float* ngam  = (const float*)d_in[19];
    const float* nbet  = (const float*)d_in[20];

    char* ws = (char*)d_ws;
    unsigned short* stb = (unsigned short*)ws;                   // 64 MiB
    short* wct = (short*)(ws + (64u << 20));                     // 1 MiB
    short* w2b = (short*)(ws + (65u << 20));                     // 512 KiB each
    short* wgb = w2b + 262144;
    float* part = (float*)(ws + (66u << 20));                    // 32 MiB (8192 x 1024)
    float* outp = (float*)d_out;

    vsn_prepack<<<dim3(192), 256, 0, stream>>>(W2, Wg, Wn1, Wns, w2b, wgb, wct);
    vsn_stage1<<<dim3(NTOK / 128, 16), 256, 0, stream>>>(
        x, W1, b1, w2b, wgb, b2, bg, Wsk, bsk, gamma, beta, stb);
    vsn_stage2a<<<dim3(NTOK / 128, KSPLIT), 512, 0, stream>>>(stb, wct, part);
    vsn_stage2b<<<dim3(NTOK / 8), 256, 0, stream>>>(
        stb, part, bn1, Wn2, bn2, Wng, bng, bns, ngam, nbet, outp);
}

// Round 9
// 185.820 us; speedup vs baseline: 1.5819x; 1.0100x over previous
//
#include <hip/hip_runtime.h>
#include <hip/hip_bf16.h>
#include <math.h>

#define NV 64
#define ND 64
#define NTOK 8192
#define LN_EPS 1e-5f
#define SROW 4096
#define WROW 4096
#define KSPLIT 8
#define KR2 (4096 / KSPLIT)     // 512
#define BK 64
#define NKC (KR2 / BK)          // 8
#define PROW2 (KSPLIT * 128)    // 1024

typedef __attribute__((ext_vector_type(8))) short s8v;    // 8 bf16 = 4 VGPR
typedef __attribute__((ext_vector_type(4))) float f4v;    // MFMA C/D
typedef __attribute__((ext_vector_type(4))) int   i4v;

__device__ __forceinline__ float sigm_f(float x) {
    return __builtin_amdgcn_rcpf(1.f + __expf(-x));
}
__device__ __forceinline__ float elu_f(float x)  { return x > 0.f ? x : (__expf(x) - 1.f); }

__device__ __forceinline__ float bf16_to_f(unsigned short s) {
    union { unsigned int u; float f; } c; c.u = ((unsigned int)s) << 16;
    return c.f;
}
__device__ __forceinline__ unsigned short bf16_rn(float f) {
    union { float f; unsigned int u; } c; c.f = f;
    return (unsigned short)((c.u + 0x8000u) >> 16);
}
// async global->LDS 16B (lds base wave-uniform; lane l writes base + l*16B)
__device__ __forceinline__ void async16(const void* g, void* l) {
    __builtin_amdgcn_global_load_lds(
        (const __attribute__((address_space(1))) unsigned int*)g,
        (__attribute__((address_space(3))) unsigned int*)l,
        16, 0, 0);
}

// ---------------- Prepack: weight transposes via LDS tiles (coalesced R+W)
__global__ __launch_bounds__(256) void vsn_prepack(
    const float* __restrict__ W2, const float* __restrict__ Wg,
    const float* __restrict__ Wn1, const float* __restrict__ Wns,
    short* __restrict__ w2b, short* __restrict__ wgb,
    short* __restrict__ wct)
{
    __shared__ float T[64][65];
    const int b = blockIdx.x, t = threadIdx.x;

    if (b < 64) {
        const float* src = W2 + (size_t)b * 4096;
        short* dst = w2b + (size_t)b * 4096;
        #pragma unroll
        for (int pass = 0; pass < 2; ++pass) {
            #pragma unroll
            for (int i = 0; i < 16; ++i) {
                int id = i * 256 + t;
                T[id & 63][id >> 6] = src[id];
            }
            __syncthreads();
            #pragma unroll
            for (int i = 0; i < 16; ++i) {
                int id = i * 256 + t;
                dst[id] = (short)bf16_rn(T[id >> 6][id & 63]);
            }
            __syncthreads();
            src = Wg + (size_t)b * 4096;
            dst = wgb + (size_t)b * 4096;
        }
    } else {
        int tb = b - 64;
        int half = tb >> 6, kt = tb & 63;
        const float* src = (half == 0 ? Wn1 : Wns) + (size_t)(kt * 64) * 64;
        #pragma unroll
        for (int i = 0; i < 16; ++i) {
            int id = i * 256 + t;
            T[id & 63][id >> 6] = src[id];
        }
        __syncthreads();
        #pragma unroll
        for (int i = 0; i < 16; ++i) {
            int id = i * 256 + t;
            int n = id >> 6, r = id & 63;
            wct[(size_t)(half * 64 + n) * WROW + kt * 64 + r] = (short)bf16_rn(T[n][r]);
        }
    }
}

// ---------------- Stage 1: verified round-0 version (~50us).
// Scattered 2B stores are fully hidden under VALU (R8 measured the LDS-staged
// alternative at +3us); plain launch_bounds (the (256,4) bound spills, R6/R7).
__global__ __launch_bounds__(256) void vsn_stage1(
    const float* __restrict__ x,
    const float* __restrict__ W1, const float* __restrict__ b1,
    const short* __restrict__ w2b, const short* __restrict__ wgb,
    const float* __restrict__ b2, const float* __restrict__ bg,
    const float* __restrict__ Wsk, const float* __restrict__ bsk,
    const float* __restrict__ gamma, const float* __restrict__ beta,
    unsigned short* __restrict__ stb)
{
    const int t = threadIdx.x;
    const int wave = t >> 6, lane = t & 63;
    const int m16 = lane & 15, quad = lane >> 4;
    const int v = blockIdx.y * 4 + wave;

    __shared__ float xs[4][32];
    __shared__ __align__(16) unsigned short h2s[4][32][72];

    float w1k[2][8], b1k[2][8];
    #pragma unroll
    for (int kt = 0; kt < 2; ++kt) {
        *(float4*)&w1k[kt][0] = *(const float4*)(W1 + v * 64 + kt * 32 + quad * 8);
        *(float4*)&w1k[kt][4] = *(const float4*)(W1 + v * 64 + kt * 32 + quad * 8 + 4);
        *(float4*)&b1k[kt][0] = *(const float4*)(b1 + v * 64 + kt * 32 + quad * 8);
        *(float4*)&b1k[kt][4] = *(const float4*)(b1 + v * 64 + kt * 32 + quad * 8 + 4);
    }
    float b2d[4], bgd[4], wskd[4], bskd[4], gamd[4], betd[4];
    #pragma unroll
    for (int ni = 0; ni < 4; ++ni) {
        int d = v * 64 + ni * 16 + m16;
        b2d[ni] = b2[d]; bgd[ni] = bg[d]; wskd[ni] = Wsk[d]; bskd[ni] = bsk[d];
        gamd[ni] = gamma[d]; betd[ni] = beta[d];
    }
    const size_t wb = (size_t)v * 4096;

    for (int tt4 = 0; tt4 < 4; ++tt4) {
        const int tile0 = blockIdx.x * 128 + tt4 * 32;

        if (lane < 32) xs[wave][lane] = x[(size_t)(tile0 + lane) * NV + v];

        s8v a[2][2];
        #pragma unroll
        for (int kt = 0; kt < 2; ++kt)
            #pragma unroll
            for (int mi = 0; mi < 2; ++mi) {
                float xv = xs[wave][mi * 16 + m16];
                float h[8];
                #pragma unroll
                for (int j = 0; j < 8; ++j) h[j] = elu_f(fmaf(xv, w1k[kt][j], b1k[kt][j]));
                i4v av;
                #pragma unroll
                for (int p = 0; p < 4; ++p) {
                    unsigned int u0 = __float_as_uint(h[2 * p]);
                    unsigned int u1 = __float_as_uint(h[2 * p + 1]);
                    av[p] = (int)((u1 & 0xffff0000u) | (u0 >> 16));
                }
                a[mi][kt] = *(s8v*)&av;
            }

        f4v hacc[2][4];
        #pragma unroll
        for (int mi = 0; mi < 2; ++mi)
            #pragma unroll
            for (int ni = 0; ni < 4; ++ni) hacc[mi][ni] = (f4v){0.f, 0.f, 0.f, 0.f};
        #pragma unroll
        for (int ni = 0; ni < 4; ++ni)
            #pragma unroll
            for (int kt = 0; kt < 2; ++kt) {
                s8v bh = *(const s8v*)(w2b + wb + (size_t)(ni * 16 + m16) * 64 + kt * 32 + quad * 8);
                #pragma unroll
                for (int mi = 0; mi < 2; ++mi)
                    hacc[mi][ni] = __builtin_amdgcn_mfma_f32_16x16x32_bf16(a[mi][kt], bh, hacc[mi][ni], 0, 0, 0);
            }
        #pragma unroll
        for (int mi = 0; mi < 2; ++mi)
            #pragma unroll
            for (int ni = 0; ni < 4; ++ni)
                #pragma unroll
                for (int r = 0; r < 4; ++r) hacc[mi][ni][r] += b2d[ni];

        #pragma unroll
        for (int mi = 0; mi < 2; ++mi)
            #pragma unroll
            for (int ni = 0; ni < 4; ++ni)
                #pragma unroll
                for (int r = 0; r < 4; ++r)
                    h2s[wave][mi * 16 + quad * 4 + r][ni * 16 + m16] =
                        (unsigned short)(__float_as_uint(hacc[mi][ni][r]) >> 16);

        s8v c[2][2];
        #pragma unroll
        for (int mi = 0; mi < 2; ++mi)
            #pragma unroll
            for (int kt = 0; kt < 2; ++kt)
                c[mi][kt] = *(const s8v*)&h2s[wave][mi * 16 + m16][kt * 32 + quad * 8];

        f4v gacc[2][4];
        #pragma unroll
        for (int mi = 0; mi < 2; ++mi)
            #pragma unroll
            for (int ni = 0; ni < 4; ++ni) gacc[mi][ni] = (f4v){0.f, 0.f, 0.f, 0.f};
        #pragma unroll
        for (int ni = 0; ni < 4; ++ni)
            #pragma unroll
            for (int kt = 0; kt < 2; ++kt) {
                s8v bh = *(const s8v*)(wgb + wb + (size_t)(ni * 16 + m16) * 64 + kt * 32 + quad * 8);
                #pragma unroll
                for (int mi = 0; mi < 2; ++mi)
                    gacc[mi][ni] = __builtin_amdgcn_mfma_f32_16x16x32_bf16(c[mi][kt], bh, gacc[mi][ni], 0, 0, 0);
            }

        {
            float xtok[2][4];
            #pragma unroll
            for (int mi = 0; mi < 2; ++mi)
                #pragma unroll
                for (int r = 0; r < 4; ++r) xtok[mi][r] = xs[wave][mi * 16 + quad * 4 + r];
            #pragma unroll
            for (int mi = 0; mi < 2; ++mi)
                #pragma unroll
                for (int ni = 0; ni < 4; ++ni)
                    #pragma unroll
                    for (int r = 0; r < 4; ++r) {
                        float g = sigm_f(gacc[mi][ni][r] + bgd[ni]);
                        gacc[mi][ni][r] = fmaf(xtok[mi][r], wskd[ni], bskd[ni]) + g * hacc[mi][ni][r];
                    }
        }

        #pragma unroll
        for (int mi = 0; mi < 2; ++mi)
            #pragma unroll
            for (int r = 0; r < 4; ++r) {
                float s0 = gacc[mi][0][r], s1 = gacc[mi][1][r], s2 = gacc[mi][2][r], s3 = gacc[mi][3][r];
                float sum = s0 + s1 + s2 + s3;
                float sq  = s0 * s0 + s1 * s1 + s2 * s2 + s3 * s3;
                #pragma unroll
                for (int m = 1; m < 16; m <<= 1) { sum += __shfl_xor(sum, m); sq += __shfl_xor(sq, m); }
                float mu  = sum * 0.015625f;
                float var = sq * 0.015625f - mu * mu;
                float rs  = __builtin_amdgcn_rsqf(var + LN_EPS);
                size_t base = (size_t)(tile0 + mi * 16 + quad * 4 + r) * SROW + (size_t)v * 64 + m16;
                #pragma unroll
                for (int ni = 0; ni < 4; ++ni)
                    stb[base + ni * 16] =
                        bf16_rn((gacc[mi][ni][r] - mu) * rs * gamd[ni] + betd[ni]);
            }
    }
}

// ---------------- Stage 2a: M=128 x N=128, KSPLIT=8, BK=64, 512 thr / 8 waves.
// Distance-2 prefetch + counted vmcnt (verified R3, the only schedule change
// that measured positive). Staging: linear LDS dest + inverse-XOR-swizzled
// source + XOR-swizzled ds_read.
__global__ __launch_bounds__(512) void vsn_stage2a(
    const unsigned short* __restrict__ stb,   // [8192][SROW]
    const short* __restrict__ wct,            // [128][WROW]
    float* __restrict__ part)                 // [8192][PROW2]
{
    const int t = threadIdx.x;
    const int wave = t >> 6, lane = t & 63;
    const int m16 = lane & 15, quad = lane >> 4;
    const int mw = wave & 3, nw = wave >> 2;
    const int tok0 = blockIdx.x * 128;
    const int s = blockIdx.y;
    const int k0 = s * KR2;

    __shared__ __align__(16) unsigned short Al[2][128 * 64];   // 16KB x2
    __shared__ __align__(16) unsigned short Bl[2][128 * 64];   // 16KB x2

    const int srow = t >> 3;            // 0..63 (+64 for q=1)
    const int schunk = t & 7;           // 16B chunk within the 128B row

    f4v acc[2][4];
    #pragma unroll
    for (int mi = 0; mi < 2; ++mi)
        #pragma unroll
        for (int nj = 0; nj < 4; ++nj) acc[mi][nj] = (f4v){0.f, 0.f, 0.f, 0.f};

    auto STAGE = [&](int buf, int kc) {
        const int kb = k0 + kc * BK;
        #pragma unroll
        for (int q = 0; q < 2; ++q) {
            const int row = srow + q * 64;
            const int sc = (schunk ^ (row & 7)) * 8;   // inverse-swizzled source col
            async16(stb + (size_t)(tok0 + row) * SROW + kb + sc,
                    &Al[buf][q * 4096 + wave * 512]);
            async16(wct + (size_t)row * WROW + kb + sc,
                    &Bl[buf][q * 4096 + wave * 512]);
        }
    };

    // prologue: 2 stages in flight (4 loads/lane each)
    STAGE(0, 0);
    STAGE(1, 1);

    for (int kc = 0; kc < NKC; ++kc) {
        const int buf = kc & 1;
        // wait for stage kc only (stage kc+1's 4 loads stay in flight)
        if (kc + 1 < NKC) asm volatile("s_waitcnt vmcnt(4)" ::: "memory");
        else              asm volatile("s_waitcnt vmcnt(0)" ::: "memory");
        __builtin_amdgcn_s_barrier();
        __builtin_amdgcn_sched_barrier(0);

        #pragma unroll
        for (int ks = 0; ks < 2; ++ks) {
            s8v af[2], bfr[4];
            #pragma unroll
            for (int mi = 0; mi < 2; ++mi) {
                int row = mw * 32 + mi * 16 + m16;
                int ch = ((ks * 4 + quad) ^ (row & 7)) * 8;     // swizzled read
                af[mi] = *(const s8v*)&Al[buf][row * 64 + ch];
            }
            #pragma unroll
            for (int nj = 0; nj < 4; ++nj) {
                int row = nw * 64 + nj * 16 + m16;
                int ch = ((ks * 4 + quad) ^ (row & 7)) * 8;
                bfr[nj] = *(const s8v*)&Bl[buf][row * 64 + ch];
            }
            #pragma unroll
            for (int mi = 0; mi < 2; ++mi)
                #pragma unroll
                for (int nj = 0; nj < 4; ++nj)
                    acc[mi][nj] = __builtin_amdgcn_mfma_f32_16x16x32_bf16(af[mi], bfr[nj], acc[mi][nj], 0, 0, 0);
        }

        // all waves done reading buf before it is overwritten by stage kc+2
        asm volatile("s_waitcnt lgkmcnt(0)" ::: "memory");
        __builtin_amdgcn_s_barrier();
        __builtin_amdgcn_sched_barrier(0);
        if (kc + 2 < NKC) STAGE(buf, kc + 2);
    }

    #pragma unroll
    for (int mi = 0; mi < 2; ++mi)
        #pragma unroll
        for (int nj = 0; nj < 4; ++nj)
            #pragma unroll
            for (int r = 0; r < 4; ++r)
                part[(size_t)(tok0 + mw * 32 + mi * 16 + quad * 4 + r) * PROW2
                     + s * 128 + nw * 64 + nj * 16 + m16] = acc[mi][nj][r];
}

// ---------------- Stage 2b: reduce 8 contiguous partials, tail GRN, softmax, weighted sum
__global__ __launch_bounds__(256) void vsn_stage2b(
    const unsigned short* __restrict__ stb, const float* __restrict__ part,
    const float* __restrict__ bn1,
    const float* __restrict__ Wn2, const float* __restrict__ bn2,
    const float* __restrict__ Wng, const float* __restrict__ bng,
    const float* __restrict__ bns,
    const float* __restrict__ ngamma, const float* __restrict__ nbeta,
    float* __restrict__ out)
{
    const int t = threadIdx.x;
    const int tok0 = blockIdx.x * 8;
    const int lane = t & 63, wv = t >> 6;

    __shared__ __align__(16) float hw1_s[8][64];
    __shared__ __align__(16) float skw_s[8][64];
    __shared__ __align__(16) float hw2_s[8][64];
    __shared__ float s2_s[8][64];
    __shared__ float w_s[8][64];

    // ---- reduce part[tok][0:8][0:128]; contiguous f4 wave-loads
    #pragma unroll
    for (int tk = 0; tk < 2; ++tk) {
        int tl = wv * 2 + tk;
        const float* pr = part + (size_t)(tok0 + tl) * PROW2
                        + (lane >> 5) * 128 + (lane & 31) * 4;
        float tv[4] = {0.f, 0.f, 0.f, 0.f};
        #pragma unroll
        for (int i = 0; i < 4; ++i) {
            float4 a = *(const float4*)(pr + i * 256);
            tv[0] += a.x; tv[1] += a.y; tv[2] += a.z; tv[3] += a.w;
        }
        #pragma unroll
        for (int c = 0; c < 4; ++c) tv[c] += __shfl_xor(tv[c], 32);
        if (lane < 16) {
            int j0 = lane * 4;
            float4 bb = *(const float4*)(bn1 + j0);
            hw1_s[tl][j0 + 0] = elu_f(tv[0] + bb.x);
            hw1_s[tl][j0 + 1] = elu_f(tv[1] + bb.y);
            hw1_s[tl][j0 + 2] = elu_f(tv[2] + bb.z);
            hw1_s[tl][j0 + 3] = elu_f(tv[3] + bb.w);
        } else if (lane < 32) {
            int j0 = (lane - 16) * 4;
            float4 bb = *(const float4*)(bns + j0);
            skw_s[tl][j0 + 0] = tv[0] + bb.x;
            skw_s[tl][j0 + 1] = tv[1] + bb.y;
            skw_s[tl][j0 + 2] = tv[2] + bb.z;
            skw_s[tl][j0 + 3] = tv[3] + bb.w;
        }
    }
    __syncthreads();

    // ---- hw2 = hw1 @ Wn2 + bn2
    #pragma unroll
    for (int i = 0; i < 2; ++i) {
        int oidx = i * 256 + t;
        int tt = oidx >> 6, jj = oidx & 63;
        float acc = bn2[jj];
        #pragma unroll
        for (int k4 = 0; k4 < 16; ++k4) {
            float4 h = *(const float4*)&hw1_s[tt][k4 * 4];
            acc += h.x * Wn2[(k4*4+0)*64+jj] + h.y * Wn2[(k4*4+1)*64+jj]
                 + h.z * Wn2[(k4*4+2)*64+jj] + h.w * Wn2[(k4*4+3)*64+jj];
        }
        hw2_s[tt][jj] = acc;
    }
    __syncthreads();

    // ---- gw = sigmoid(hw2 @ Wng + bng); s2 = skw + gw*hw2
    #pragma unroll
    for (int i = 0; i < 2; ++i) {
        int oidx = i * 256 + t;
        int tt = oidx >> 6, vv = oidx & 63;
        float acc = bng[vv];
        #pragma unroll
        for (int k4 = 0; k4 < 16; ++k4) {
            float4 h = *(const float4*)&hw2_s[tt][k4 * 4];
            acc += h.x * Wng[(k4*4+0)*64+vv] + h.y * Wng[(k4*4+1)*64+vv]
                 + h.z * Wng[(k4*4+2)*64+vv] + h.w * Wng[(k4*4+3)*64+vv];
        }
        float gw = sigm_f(acc);
        s2_s[tt][vv] = skw_s[tt][vv] + gw * hw2_s[tt][vv];
    }
    __syncthreads();

    // ---- HOISTED stb loads for the weighted sum
    const int vloc = lane >> 3, d8 = (lane & 7) * 8;
    s8v r0[8], r1[8];
    {
        const short* s0 = (const short*)stb + (size_t)(tok0 + wv * 2) * SROW + d8;
        const short* s1 = s0 + SROW;
        #pragma unroll
        for (int vc = 0; vc < 8; ++vc) {
            r0[vc] = *(const s8v*)(s0 + (vc * 8 + vloc) * 64);
            r1[vc] = *(const s8v*)(s1 + (vc * 8 + vloc) * 64);
        }
    }

    // ---- LN over v + softmax; 16 lanes per token
    if (t < 128) {
        int tt = t >> 4, l = t & 15;
        float z[4]; float sum = 0.f, sq = 0.f;
        #pragma unroll
        for (int i = 0; i < 4; ++i) { z[i] = s2_s[tt][l + 16 * i]; sum += z[i]; sq += z[i] * z[i]; }
        #pragma unroll
        for (int m = 1; m < 16; m <<= 1) { sum += __shfl_xor(sum, m); sq += __shfl_xor(sq, m); }
        float mu  = sum * 0.015625f;
        float var = sq * 0.015625f - mu * mu;
        float rs  = __builtin_amdgcn_rsqf(var + LN_EPS);
        float ln[4]; float mx = -1e30f;
        #pragma unroll
        for (int i = 0; i < 4; ++i) {
            ln[i] = (z[i] - mu) * rs * ngamma[l + 16 * i] + nbeta[l + 16 * i];
            mx = fmaxf(mx, ln[i]);
        }
        #pragma unroll
        for (int m = 1; m < 16; m <<= 1) mx = fmaxf(mx, __shfl_xor(mx, m));
        float es = 0.f; float ev[4];
        #pragma unroll
        for (int i = 0; i < 4; ++i) { ev[i] = __expf(ln[i] - mx); es += ev[i]; }
        #pragma unroll
        for (int m = 1; m < 16; m <<= 1) es += __shfl_xor(es, m);
        float inv = __builtin_amdgcn_rcpf(es);
        #pragma unroll
        for (int i = 0; i < 4; ++i) w_s[tt][l + 16 * i] = ev[i] * inv;
    }
    __syncthreads();

    // ---- weighted sum from the hoisted registers
    {
        float acc0[8], acc1[8];
        #pragma unroll
        for (int j = 0; j < 8; ++j) { acc0[j] = 0.f; acc1[j] = 0.f; }
        #pragma unroll
        for (int vc = 0; vc < 8; ++vc) {
            int v = vc * 8 + vloc;
            float w0 = w_s[wv * 2][v], w1 = w_s[wv * 2 + 1][v];
            #pragma unroll
            for (int j = 0; j < 8; ++j) {
                acc0[j] = fmaf(w0, bf16_to_f((unsigned short)r0[vc][j]), acc0[j]);
                acc1[j] = fmaf(w1, bf16_to_f((unsigned short)r1[vc][j]), acc1[j]);
            }
        }
        #pragma unroll
        for (int m = 8; m <= 32; m <<= 1)
            #pragma unroll
            for (int j = 0; j < 8; ++j) {
                acc0[j] += __shfl_xor(acc0[j], m);
                acc1[j] += __shfl_xor(acc1[j], m);
            }
        if (lane < 8) {
            float* op = out + (size_t)(tok0 + wv * 2) * 64 + lane * 8;
            *(float4*)op       = make_float4(acc0[0], acc0[1], acc0[2], acc0[3]);
            *(float4*)(op + 4) = make_float4(acc0[4], acc0[5], acc0[6], acc0[7]);
            op += 64;
            *(float4*)op       = make_float4(acc1[0], acc1[1], acc1[2], acc1[3]);
            *(float4*)(op + 4) = make_float4(acc1[4], acc1[5], acc1[6], acc1[7]);
        }
    }
}

extern "C" void kernel_launch(void* const* d_in, const int* in_sizes, int n_in,
                              void* d_out, int out_size, void* d_ws, size_t ws_size,
                              hipStream_t stream) {
    const float* x     = (const float*)d_in[0];
    const float* W1    = (const float*)d_in[1];
    const float* b1    = (const float*)d_in[2];
    const float* W2    = (const float*)d_in[3];
    const float* b2    = (const float*)d_in[4];
    const float* Wg    = (const float*)d_in[5];
    const float* bg    = (const float*)d_in[6];
    const float* Wsk   = (const float*)d_in[7];
    const float* bsk   = (const float*)d_in[8];
    const float* gamma = (const float*)d_in[9];
    const float* beta  = (const float*)d_in[10];
    const float* Wn1   = (const float*)d_in[11];
    const float* bn1   = (const float*)d_in[12];
    const float* Wn2   = (const float*)d_in[13];
    const float* bn2   = (const float*)d_in[14];
    const float* Wng   = (const float*)d_in[15];
    const float* bng   = (const float*)d_in[16];
    const float* Wns   = (const float*)d_in[17];
    const float* bns   = (const float*)d_in[18];
    const float* ngam  = (const float*)d_in[19];
    const float* nbet  = (const float*)d_in[20];

    char* ws = (char*)d_ws;
    unsigned short* stb = (unsigned short*)ws;                   // 64 MiB
    short* wct = (short*)(ws + (64u << 20));                     // 1 MiB
    short* w2b = (short*)(ws + (65u << 20));                     // 512 KiB each
    short* wgb = w2b + 262144;
    float* part = (float*)(ws + (66u << 20));                    // 32 MiB (8192 x 1024)
    float* outp = (float*)d_out;

    vsn_prepack<<<dim3(192), 256, 0, stream>>>(W2, Wg, Wn1, Wns, w2b, wgb, wct);
    vsn_stage1<<<dim3(NTOK / 128, 16), 256, 0, stream>>>(
        x, W1, b1, w2b, wgb, b2, bg, Wsk, bsk, gamma, beta, stb);
    vsn_stage2a<<<dim3(NTOK / 128, KSPLIT), 512, 0, stream>>>(stb, wct, part);
    vsn_stage2b<<<dim3(NTOK / 8), 256, 0, stream>>>(
        stb, part, bn1, Wn2, bn2, Wng, bng, bns, ngam, nbet, outp);
}